// Round 9
// baseline (119.555 us; speedup 1.0000x reference)
//
#include <hip/hip_runtime.h>
#include <hip/hip_bf16.h>

typedef __hip_bfloat16 bf16;

// ---------- constants ----------
// B=2, N=2048, C=128, H=8, hd=16, branches=3, hid=768
// rows per branch = B*N = 4096; 3C = 384
// I/O fp32; intermediates bf16 except xc (fp32 residual). Weights pre-transposed
// to bf16 Wt[N][K] by k_wt_all. Q is pre-scaled by 0.25*log2e (exp2-domain softmax).
// V is stored TRANSPOSED per head (V^T[bh][d][key]) by k_qkv_m so attention needs
// no LDS and no barriers. Attention is split-K (2 x 1024 keys), merged by k_attn_red.

static __device__ __forceinline__ float b2f(bf16 h) { return __bfloat162float(h); }
static __device__ __forceinline__ bf16 f2b(float f) { return __float2bfloat16(f); }
static __device__ __forceinline__ unsigned short f2bu(float f) {
    bf16 h = f2b(f);
    return *reinterpret_cast<unsigned short*>(&h);
}
static __device__ __forceinline__ float bs2f(short s) {
    return __uint_as_float(((unsigned)(unsigned short)s) << 16);
}

typedef __attribute__((ext_vector_type(8))) short short8;
typedef __attribute__((ext_vector_type(4))) short short4v;
typedef __attribute__((ext_vector_type(16))) float f32x16;
typedef __attribute__((ext_vector_type(2))) int int2v;

#define QSCALE 0.36067376022224085f  // 0.25 * log2(e)

// partner-half exchange via permlane32_swap (VALU)
static __device__ __forceinline__ float xhalf(float x, int hi) {
    auto r = __builtin_amdgcn_permlane32_swap(__float_as_int(x), __float_as_int(x), false, false);
    return __int_as_float(hi ? r[0] : r[1]);
}

// ================= K0: all weight transposes+convert in one launch =================
__global__ __launch_bounds__(256) void k_wt_all(const float* __restrict__ qkv_w, const float* __restrict__ proj_w,
                                                const float* __restrict__ fc1_w, const float* __restrict__ fc2_w,
                                                bf16* __restrict__ wtq, bf16* __restrict__ wtp,
                                                bf16* __restrict__ wt1, bf16* __restrict__ wt2) {
    int idx = blockIdx.x * 256 + threadIdx.x;   // < 786432
    if (idx < 147456) {
        int b = idx / 49152, i2 = idx % 49152;
        int n = i2 >> 7, k = i2 & 127;
        wtq[idx] = f2b(qkv_w[b * 49152 + k * 384 + n]);
    } else if (idx < 196608) {
        int j = idx - 147456;
        int b = j / 16384, i2 = j % 16384;
        int n = i2 >> 7, k = i2 & 127;
        wtp[j] = f2b(proj_w[b * 16384 + k * 128 + n]);
    } else if (idx < 491520) {
        int j = idx - 196608;
        int n = j / 384, k = j - n * 384;
        wt1[j] = f2b(fc1_w[k * 768 + n]);
    } else {
        int j = idx - 491520;
        int n = j / 768, k = j - n * 768;
        wt2[j] = f2b(fc2_w[k * 384 + n]);
    }
}

// ================= shared MFMA GEMM tile: C64x64 = A[M,K] . Wt[N,K]^T =================
__device__ __forceinline__ f32x16 gemm_tile(const short* __restrict__ A, const short* __restrict__ W,
                                            int K, int rowbase, int colbase,
                                            short* als, short* wls) {
    int tid = threadIdx.x;
    int wid = tid >> 6, lane = tid & 63;
    int hi = lane >> 5, l31 = lane & 31;
    int wm = wid >> 1, wn = wid & 1;
    int sr = tid >> 3, skb = tid & 7;   // staging: row (0..31), k-block (0..7)
    f32x16 acc;
#pragma unroll
    for (int i = 0; i < 16; ++i) acc[i] = 0.f;
    for (int k0 = 0; k0 < K; k0 += 64) {
        __syncthreads();
#pragma unroll
        for (int pass = 0; pass < 2; ++pass) {
            int r = sr + pass * 32;
            short8 av = *(const short8*)&A[(size_t)(rowbase + r) * K + k0 + skb * 8];
            *(short8*)&als[r * 64 + ((skb ^ (r & 7)) * 8)] = av;
            short8 wv = *(const short8*)&W[(size_t)(colbase + r) * K + k0 + skb * 8];
            *(short8*)&wls[r * 64 + ((skb ^ (r & 7)) * 8)] = wv;
        }
        __syncthreads();
#pragma unroll
        for (int ks = 0; ks < 4; ++ks) {
            int ra = wm * 32 + l31;
            int rb = wn * 32 + l31;
            int kb = ks * 2 + hi;
            short8 af = *(const short8*)&als[ra * 64 + ((kb ^ (ra & 7)) * 8)];
            short8 bf = *(const short8*)&wls[rb * 64 + ((kb ^ (rb & 7)) * 8)];
            acc = __builtin_amdgcn_mfma_f32_32x32x16_bf16(af, bf, acc, 0, 0, 0);
        }
    }
    return acc;
}

// ================= K1: LN1 for all 3 branches =================
__global__ __launch_bounds__(256) void k_ln1(const float* __restrict__ x1, const float* __restrict__ x2,
                                             const float* __restrict__ x3, const float* __restrict__ g,
                                             const float* __restrict__ b, bf16* __restrict__ xn) {
    int tid = threadIdx.x;
    int wave = tid >> 6, lane = tid & 63;
    int grow = blockIdx.x * 4 + wave;      // 0..12287
    int branch = grow >> 12;
    const float* xp = (branch == 0) ? x1 : (branch == 1 ? x2 : x3);
    const float* row = xp + (size_t)(grow & 4095) * 128;
    float2 a = *reinterpret_cast<const float2*>(&row[2 * lane]);
    float s = a.x + a.y, sq = a.x * a.x + a.y * a.y;
#pragma unroll
    for (int off = 32; off >= 1; off >>= 1) { s += __shfl_xor(s, off); sq += __shfl_xor(sq, off); }
    float mean = s * (1.f / 128.f);
    float var = sq * (1.f / 128.f) - mean * mean;
    float rstd = rsqrtf(var + 1e-5f);
    float2 gv = *reinterpret_cast<const float2*>(&g[branch * 128 + 2 * lane]);
    float2 bv = *reinterpret_cast<const float2*>(&b[branch * 128 + 2 * lane]);
    bf16* orow = xn + (size_t)grow * 128;
    orow[2 * lane] = f2b((a.x - mean) * rstd * gv.x + bv.x);
    orow[2 * lane + 1] = f2b((a.y - mean) * rstd * gv.y + bv.y);
}

// ================= K2: QKV GEMM (MFMA); Q pre-scaled; V stored transposed =================
__global__ __launch_bounds__(256) void k_qkv_m(const bf16* __restrict__ xn, const bf16* __restrict__ wt,
                                               bf16* __restrict__ q, bf16* __restrict__ k, bf16* __restrict__ v) {
    __shared__ short als[64 * 64];
    __shared__ short wls[64 * 64];
    int branch = blockIdx.z;
    const short* A = (const short*)xn + (size_t)branch * 4096 * 128;
    const short* W = (const short*)wt + (size_t)branch * 384 * 128;
    int rowbase = blockIdx.x * 64, colbase = blockIdx.y * 64;
    f32x16 acc = gemm_tile(A, W, 128, rowbase, colbase, als, wls);
    int tid = threadIdx.x, wid = tid >> 6, lane = tid & 63;
    int hi = lane >> 5, l31 = lane & 31;
    int wm = wid >> 1, wn = wid & 1;
    int c = colbase + wn * 32 + l31;        // 0..383
    int which = c >> 7, h = (c >> 4) & 7, d = c & 15;   // which is block-uniform
    if (which < 2) {
        bf16* dst = (which == 0) ? q : k;
        float scl = (which == 0) ? QSCALE : 1.0f;
#pragma unroll
        for (int i = 0; i < 16; ++i) {
            int mrow = (i & 3) + 8 * (i >> 2) + 4 * hi;
            int token = rowbase + wm * 32 + mrow;
            int bb = token >> 11, n = token & 2047;
            dst[((((size_t)branch * 2 + bb) * 8 + h) * 2048 + n) * 16 + d] = f2b(acc[i] * scl);
        }
    } else {
        // V^T layout: v[(bh*16 + d)*2048 + n]
#pragma unroll
        for (int i = 0; i < 16; ++i) {
            int mrow = (i & 3) + 8 * (i >> 2) + 4 * hi;
            int token = rowbase + wm * 32 + mrow;
            int bb = token >> 11, n = token & 2047;
            v[((((size_t)branch * 2 + bb) * 8 + h) * 16 + d) * 2048 + n] = f2b(acc[i]);
        }
    }
}

// ================= K3: MFMA attention — barrier-free, LDS-free, split-K (2 x 1024) =================
// 128 threads = 2 independent waves; wave owns 32 q-rows; grid (48, 32, 2) = 3072 blocks.
// Per 64 keys: 2 K loads + 4 V^T loads (global, L2-hot) -> 2 QK MFMA (C=-m) ->
// 32 exp2 -> psum/threshold -> cvt_pk/permlane -> 4 PV MFMA. No LDS, no barriers.
__global__ __launch_bounds__(128, 4) void k_attn(const bf16* __restrict__ qg, const bf16* __restrict__ kg,
                                                 const bf16* __restrict__ vg, bf16* __restrict__ pacc,
                                                 float2* __restrict__ psm) {
    int bh = blockIdx.x;            // (branch*2+b)*8+h
    int qblk = blockIdx.y;          // 0..31
    int split = blockIdx.z;         // 0..1
    size_t base = (size_t)bh * (2048 * 16);
    size_t baset = (size_t)bh * (16 * 2048);   // V^T base
    int tid = threadIdx.x, wave = tid >> 6, lane = tid & 63;
    int hi = lane >> 5, l31 = lane & 31;
    int qrow = qblk * 64 + wave * 32 + l31;
    const short* qs = (const short*)qg;
    const short* ks = (const short*)kg;
    const short* vts = (const short*)vg;
    short8 qf = *(const short8*)&qs[base + (size_t)qrow * 16 + hi * 8];
    int d = lane & 15;
    const short* vrow = &vts[baset + (size_t)d * 2048 + hi * 8];

    f32x16 acc;
    f32x16 negm;
#pragma unroll
    for (int r = 0; r < 16; ++r) { acc[r] = 0.f; negm[r] = -16.f; }
    float m = 16.f, sum = 0.f;

    int kbeg = split * 1024, kend = kbeg + 1024;

    for (int c0 = kbeg; c0 < kend; c0 += 64) {
        short8 kf0 = *(const short8*)&ks[base + (size_t)(c0 + l31) * 16 + hi * 8];
        short8 kf1 = *(const short8*)&ks[base + (size_t)(c0 + 32 + l31) * 16 + hi * 8];
        short8 vf1 = *(const short8*)&vrow[c0];
        short8 vf2 = *(const short8*)&vrow[c0 + 16];
        short8 vf3 = *(const short8*)&vrow[c0 + 32];
        short8 vf4 = *(const short8*)&vrow[c0 + 48];
        // QK^T with -m folded into C: output = s - m (exp2 domain)
        f32x16 pa = __builtin_amdgcn_mfma_f32_32x32x16_bf16(kf0, qf, negm, 0, 0, 0);
        f32x16 pb = __builtin_amdgcn_mfma_f32_32x32x16_bf16(kf1, qf, negm, 0, 0, 0);
#pragma unroll
        for (int r = 0; r < 16; ++r) pa[r] = __builtin_amdgcn_exp2f(pa[r]);
#pragma unroll
        for (int r = 0; r < 16; ++r) pb[r] = __builtin_amdgcn_exp2f(pb[r]);
        float e0 = 0.f, e1 = 0.f, e2 = 0.f, e3 = 0.f;
#pragma unroll
        for (int r = 0; r < 16; r += 4) { e0 += pa[r]; e1 += pa[r + 1]; e2 += pa[r + 2]; e3 += pa[r + 3]; }
#pragma unroll
        for (int r = 0; r < 16; r += 4) { e0 += pb[r]; e1 += pb[r + 1]; e2 += pb[r + 2]; e3 += pb[r + 3]; }
        float psum = (e0 + e1) + (e2 + e3);
        if (__any(psum > 256.f)) {
            float p0 = fmaxf(pa[0], pa[1]), p1 = fmaxf(pa[2], pa[3]);
#pragma unroll
            for (int r = 4; r < 16; r += 4) { p0 = fmaxf(p0, fmaxf(pa[r], pa[r + 1])); p1 = fmaxf(p1, fmaxf(pa[r + 2], pa[r + 3])); }
#pragma unroll
            for (int r = 0; r < 16; r += 4) { p0 = fmaxf(p0, fmaxf(pb[r], pb[r + 1])); p1 = fmaxf(p1, fmaxf(pb[r + 2], pb[r + 3])); }
            float pmax = fmaxf(p0, p1);
            pmax = fmaxf(pmax, xhalf(pmax, hi));
            float delta = fmaxf(0.f, __log2f(pmax));
            float fac = __builtin_amdgcn_exp2f(-delta);
            m += delta;
#pragma unroll
            for (int r = 0; r < 16; ++r) negm[r] = -m;
            sum *= fac; psum *= fac;
#pragma unroll
            for (int r = 0; r < 16; ++r) { pa[r] *= fac; pb[r] *= fac; acc[r] *= fac; }
        }
        sum += psum;
        unsigned wa[8], wb[8];
#pragma unroll
        for (int e = 0; e < 8; ++e) {
            unsigned t;
            asm("v_cvt_pk_bf16_f32 %0, %1, %2" : "=v"(t) : "v"(pa[2 * e]), "v"(pa[2 * e + 1]));
            wa[e] = t;
            asm("v_cvt_pk_bf16_f32 %0, %1, %2" : "=v"(t) : "v"(pb[2 * e]), "v"(pb[2 * e + 1]));
            wb[e] = t;
        }
        union { unsigned u[4]; short8 v; } b1, b2, b3, b4;
        {
            auto r0 = __builtin_amdgcn_permlane32_swap((int)wa[0], (int)wa[2], false, false);
            b1.u[0] = (unsigned)r0[0]; b1.u[2] = (unsigned)r0[1];
            auto r1 = __builtin_amdgcn_permlane32_swap((int)wa[1], (int)wa[3], false, false);
            b1.u[1] = (unsigned)r1[0]; b1.u[3] = (unsigned)r1[1];
            auto r2 = __builtin_amdgcn_permlane32_swap((int)wa[4], (int)wa[6], false, false);
            b2.u[0] = (unsigned)r2[0]; b2.u[2] = (unsigned)r2[1];
            auto r3 = __builtin_amdgcn_permlane32_swap((int)wa[5], (int)wa[7], false, false);
            b2.u[1] = (unsigned)r3[0]; b2.u[3] = (unsigned)r3[1];
            auto r4 = __builtin_amdgcn_permlane32_swap((int)wb[0], (int)wb[2], false, false);
            b3.u[0] = (unsigned)r4[0]; b3.u[2] = (unsigned)r4[1];
            auto r5 = __builtin_amdgcn_permlane32_swap((int)wb[1], (int)wb[3], false, false);
            b3.u[1] = (unsigned)r5[0]; b3.u[3] = (unsigned)r5[1];
            auto r6 = __builtin_amdgcn_permlane32_swap((int)wb[4], (int)wb[6], false, false);
            b4.u[0] = (unsigned)r6[0]; b4.u[2] = (unsigned)r6[1];
            auto r7 = __builtin_amdgcn_permlane32_swap((int)wb[5], (int)wb[7], false, false);
            b4.u[1] = (unsigned)r7[0]; b4.u[3] = (unsigned)r7[1];
        }
        acc = __builtin_amdgcn_mfma_f32_32x32x16_bf16(vf1, b1.v, acc, 0, 0, 0);
        acc = __builtin_amdgcn_mfma_f32_32x32x16_bf16(vf2, b2.v, acc, 0, 0, 0);
        acc = __builtin_amdgcn_mfma_f32_32x32x16_bf16(vf3, b3.v, acc, 0, 0, 0);
        acc = __builtin_amdgcn_mfma_f32_32x32x16_bf16(vf4, b4.v, acc, 0, 0, 0);
    }
    // epilogue: write partials (unnormalized acc in bf16, per-qrow sum & m in f32)
    float sumt = sum + xhalf(sum, hi);
    size_t pidx = ((size_t)(split * 48 + bh) * 2048 + qrow) * 16;
    unsigned u0 = (unsigned)f2bu(acc[0]) | ((unsigned)f2bu(acc[1]) << 16);
    unsigned u1 = (unsigned)f2bu(acc[2]) | ((unsigned)f2bu(acc[3]) << 16);
    unsigned u2 = (unsigned)f2bu(acc[4]) | ((unsigned)f2bu(acc[5]) << 16);
    unsigned u3 = (unsigned)f2bu(acc[6]) | ((unsigned)f2bu(acc[7]) << 16);
    short* pp = (short*)pacc;
    int2v w01; w01.x = (int)u0; w01.y = (int)u1;
    int2v w23; w23.x = (int)u2; w23.y = (int)u3;
    *(int2v*)&pp[pidx + 4 * hi] = w01;          // d = 4*hi .. 4*hi+3
    *(int2v*)&pp[pidx + 8 + 4 * hi] = w23;      // d = 8+4*hi .. 11+4*hi
    if (hi == 0) {
        float2 sm; sm.x = sumt; sm.y = m;
        psm[(size_t)(split * 48 + bh) * 2048 + qrow] = sm;
    }
}

// ================= K3b: split-K merge -> o bf16 [branch*4096+bb*2048+n][128] =================
__global__ __launch_bounds__(256) void k_attn_red(const bf16* __restrict__ pacc, const float2* __restrict__ psm,
                                                  bf16* __restrict__ o) {
    int t = blockIdx.x * 256 + threadIdx.x;    // < 196608
    int hi = t & 1;
    int qrow = (t >> 1) & 2047;
    int bh = t >> 12;
    size_t ridx = (size_t)bh * 2048 + qrow;
    float2 sm0 = psm[ridx];
    float2 sm1 = psm[(size_t)48 * 2048 + ridx];
    float mp = fmaxf(sm0.y, sm1.y);
    float w0 = __builtin_amdgcn_exp2f(sm0.y - mp);
    float w1 = __builtin_amdgcn_exp2f(sm1.y - mp);
    float inv = 1.f / (sm0.x * w0 + sm1.x * w1);
    w0 *= inv; w1 *= inv;
    const short* p0 = (const short*)pacc + ridx * 16;
    const short* p1 = (const short*)pacc + (size_t)48 * 2048 * 16 + ridx * 16;
    short4v a0 = *(const short4v*)&p0[4 * hi];
    short4v c0 = *(const short4v*)&p0[8 + 4 * hi];
    short4v a1 = *(const short4v*)&p1[4 * hi];
    short4v c1 = *(const short4v*)&p1[8 + 4 * hi];
    unsigned u0, u1, u2, u3;
    {
        float f0 = bs2f(a0[0]) * w0 + bs2f(a1[0]) * w1;
        float f1 = bs2f(a0[1]) * w0 + bs2f(a1[1]) * w1;
        float f2 = bs2f(a0[2]) * w0 + bs2f(a1[2]) * w1;
        float f3 = bs2f(a0[3]) * w0 + bs2f(a1[3]) * w1;
        u0 = (unsigned)f2bu(f0) | ((unsigned)f2bu(f1) << 16);
        u1 = (unsigned)f2bu(f2) | ((unsigned)f2bu(f3) << 16);
        float g0 = bs2f(c0[0]) * w0 + bs2f(c1[0]) * w1;
        float g1 = bs2f(c0[1]) * w0 + bs2f(c1[1]) * w1;
        float g2 = bs2f(c0[2]) * w0 + bs2f(c1[2]) * w1;
        float g3 = bs2f(c0[3]) * w0 + bs2f(c1[3]) * w1;
        u2 = (unsigned)f2bu(g0) | ((unsigned)f2bu(g1) << 16);
        u3 = (unsigned)f2bu(g2) | ((unsigned)f2bu(g3) << 16);
    }
    int branch = bh >> 4, bb = (bh >> 3) & 1, h = bh & 7;
    size_t orow = (size_t)branch * 4096 + (size_t)bb * 2048 + qrow;
    short* op = (short*)o;
    int2v w01; w01.x = (int)u0; w01.y = (int)u1;
    int2v w23; w23.x = (int)u2; w23.y = (int)u3;
    *(int2v*)&op[orow * 128 + h * 16 + 4 * hi] = w01;
    *(int2v*)&op[orow * 128 + h * 16 + 8 + 4 * hi] = w23;
}

// ================= K4: proj GEMM (MFMA) + bias + residual -> xc[4096][384] fp32 =================
__global__ __launch_bounds__(256) void k_proj_m(const bf16* __restrict__ ob, const bf16* __restrict__ wt,
                                                const float* __restrict__ pb, const float* __restrict__ x1,
                                                const float* __restrict__ x2, const float* __restrict__ x3,
                                                float* __restrict__ xc) {
    __shared__ short als[64 * 64];
    __shared__ short wls[64 * 64];
    int branch = blockIdx.z;
    const short* A = (const short*)ob + (size_t)branch * 4096 * 128;
    const short* W = (const short*)wt + (size_t)branch * 128 * 128;
    int rowbase = blockIdx.x * 64, colbase = blockIdx.y * 64;
    f32x16 acc = gemm_tile(A, W, 128, rowbase, colbase, als, wls);
    int tid = threadIdx.x, wid = tid >> 6, lane = tid & 63;
    int hi = lane >> 5, l31 = lane & 31;
    int wm = wid >> 1, wn = wid & 1;
    int c = colbase + wn * 32 + l31;        // 0..127
    float bias = pb[branch * 128 + c];
    const float* xp = (branch == 0) ? x1 : (branch == 1 ? x2 : x3);
#pragma unroll
    for (int i = 0; i < 16; ++i) {
        int mrow = (i & 3) + 8 * (i >> 2) + 4 * hi;
        int row = rowbase + wm * 32 + mrow;
        xc[(size_t)row * 384 + branch * 128 + c] = acc[i] + bias + xp[(size_t)row * 128 + c];
    }
}

// ================= K5: LN2 over 384 features =================
__global__ __launch_bounds__(256) void k_ln2(const float* __restrict__ xc, const float* __restrict__ g,
                                             const float* __restrict__ b, bf16* __restrict__ xcn) {
    int tid = threadIdx.x, wave = tid >> 6, lane = tid & 63;
    int row = blockIdx.x * 4 + wave;  // 0..4095
    const float* rp = xc + (size_t)row * 384;
    float v[6];
    float s = 0.f, sq = 0.f;
#pragma unroll
    for (int i = 0; i < 6; ++i) {
        v[i] = rp[lane + i * 64];
        s += v[i]; sq += v[i] * v[i];
    }
#pragma unroll
    for (int off = 32; off >= 1; off >>= 1) { s += __shfl_xor(s, off); sq += __shfl_xor(sq, off); }
    float mean = s * (1.f / 384.f);
    float var = sq * (1.f / 384.f) - mean * mean;
    float rstd = rsqrtf(var + 1e-5f);
    bf16* op = xcn + (size_t)row * 384;
#pragma unroll
    for (int i = 0; i < 6; ++i) {
        int c = lane + i * 64;
        op[c] = f2b((v[i] - mean) * rstd * g[c] + b[c]);
    }
}

// ================= K6: FC1 GEMM (MFMA) + bias + exact GELU -> h bf16 =================
__global__ __launch_bounds__(256) void k_fc1_m(const bf16* __restrict__ xcn, const bf16* __restrict__ wt,
                                               const float* __restrict__ bias, bf16* __restrict__ h) {
    __shared__ short als[64 * 64];
    __shared__ short wls[64 * 64];
    const short* A = (const short*)xcn;
    const short* W = (const short*)wt;
    int rowbase = blockIdx.x * 64, colbase = blockIdx.y * 64;
    f32x16 acc = gemm_tile(A, W, 384, rowbase, colbase, als, wls);
    int tid = threadIdx.x, wid = tid >> 6, lane = tid & 63;
    int hi = lane >> 5, l31 = lane & 31;
    int wm = wid >> 1, wn = wid & 1;
    int c = colbase + wn * 32 + l31;        // 0..767
    float bs = bias[c];
#pragma unroll
    for (int i = 0; i < 16; ++i) {
        int mrow = (i & 3) + 8 * (i >> 2) + 4 * hi;
        int row = rowbase + wm * 32 + mrow;
        float vv = acc[i] + bs;
        float ge = 0.5f * vv * (1.f + erff(vv * 0.70710678118f));
        h[(size_t)row * 768 + c] = f2b(ge);
    }
}

// ================= K7: FC2 GEMM (MFMA) + bias + residual -> split fp32 outputs =================
__global__ __launch_bounds__(256) void k_fc2_m(const bf16* __restrict__ h, const bf16* __restrict__ wt,
                                               const float* __restrict__ bias, const float* __restrict__ xc,
                                               float* __restrict__ outp) {
    __shared__ short als[64 * 64];
    __shared__ short wls[64 * 64];
    const short* A = (const short*)h;
    const short* W = (const short*)wt;
    int rowbase = blockIdx.x * 64, colbase = blockIdx.y * 64;
    f32x16 acc = gemm_tile(A, W, 768, rowbase, colbase, als, wls);
    int tid = threadIdx.x, wid = tid >> 6, lane = tid & 63;
    int hi = lane >> 5, l31 = lane & 31;
    int wm = wid >> 1, wn = wid & 1;
    int c = colbase + wn * 32 + l31;        // 0..383
    float bs = bias[c];
    int which = c >> 7, cc = c & 127;
#pragma unroll
    for (int i = 0; i < 16; ++i) {
        int mrow = (i & 3) + 8 * (i >> 2) + 4 * hi;
        int row = rowbase + wm * 32 + mrow;
        outp[(size_t)which * 524288 + (size_t)row * 128 + cc] = acc[i] + bs + xc[(size_t)row * 384 + c];
    }
}

// ================= launch =================
extern "C" void kernel_launch(void* const* d_in, const int* in_sizes, int n_in,
                              void* d_out, int out_size, void* d_ws, size_t ws_size,
                              hipStream_t stream) {
    const float* x1     = (const float*)d_in[0];
    const float* x2     = (const float*)d_in[1];
    const float* x3     = (const float*)d_in[2];
    const float* ln1_g  = (const float*)d_in[3];
    const float* ln1_b  = (const float*)d_in[4];
    const float* qkv_w  = (const float*)d_in[5];
    const float* proj_w = (const float*)d_in[6];
    const float* proj_b = (const float*)d_in[7];
    const float* ln2_g  = (const float*)d_in[8];
    const float* ln2_b  = (const float*)d_in[9];
    const float* fc1_w  = (const float*)d_in[10];
    const float* fc1_b  = (const float*)d_in[11];
    const float* fc2_w  = (const float*)d_in[12];
    const float* fc2_b  = (const float*)d_in[13];

    char* ws = (char*)d_ws;
    const size_t SB = 3145728;  // bf16 buffer of 1.5M elems
    bf16* xn  = (bf16*)(ws + 0 * SB);
    bf16* qb  = (bf16*)(ws + 1 * SB);
    bf16* kb  = (bf16*)(ws + 2 * SB);
    bf16* vb  = (bf16*)(ws + 3 * SB);   // holds V^T[bh][d][key]
    bf16* ob  = (bf16*)(ws + 4 * SB);
    float* xc = (float*)(ws + 5 * SB);            // 4096*384*4 = 6291456 B
    bf16* xcn = (bf16*)(ws + 5 * SB + 6291456);   // 3145728 B
    bf16* hb  = (bf16*)(ws + 6 * SB + 6291456);   // 4096*768*2 = 6291456 B
    char* wbase = ws + 31457280;
    bf16* wtq = (bf16*)(wbase);                   // 3*384*128*2 = 294912
    bf16* wtp = (bf16*)(wbase + 294912);          // 3*128*128*2 = 98304
    bf16* wt1 = (bf16*)(wbase + 393216);          // 768*384*2   = 589824
    bf16* wt2 = (bf16*)(wbase + 983040);          // 384*768*2   = 589824
    // total = 33030144 B (~31.5 MB)
    // Split-K attention partials OVERLAY xcn+hb (both written only after attention):
    bf16*  pacc = (bf16*)(ws + 22020096);         // 2*48*2048*16*2 = 6291456 B
    float2* psm = (float2*)(ws + 28311552);       // 2*48*2048*8    = 1572864 B

    k_wt_all<<<3072, 256, 0, stream>>>(qkv_w, proj_w, fc1_w, fc2_w, wtq, wtp, wt1, wt2);
    k_ln1<<<3072, 256, 0, stream>>>(x1, x2, x3, ln1_g, ln1_b, xn);
    k_qkv_m<<<dim3(64, 6, 3), 256, 0, stream>>>(xn, wtq, qb, kb, vb);
    k_attn<<<dim3(48, 32, 2), 128, 0, stream>>>(qb, kb, vb, pacc, psm);
    k_attn_red<<<768, 256, 0, stream>>>(pacc, psm, ob);
    k_proj_m<<<dim3(64, 2, 3), 256, 0, stream>>>(ob, wtp, proj_b, x1, x2, x3, xc);
    k_ln2<<<1024, 256, 0, stream>>>(xc, ln2_g, ln2_b, xcn);
    k_fc1_m<<<dim3(64, 12, 1), 256, 0, stream>>>(xcn, wt1, fc1_b, hb);
    k_fc2_m<<<dim3(64, 6, 1), 256, 0, stream>>>(hb, wt2, fc2_b, xc, (float*)d_out);
}

// Round 10
// 104.889 us; speedup vs baseline: 1.1398x; 1.1398x over previous
//
#include <hip/hip_runtime.h>
#include <hip/hip_bf16.h>

typedef __hip_bfloat16 bf16;

// ---------- constants ----------
// B=2, N=2048, C=128, H=8, hd=16, branches=3, hid=768
// rows per branch = B*N = 4096; 3C = 384
// I/O fp32; intermediates bf16 except xc (fp32 residual). Weights pre-transposed
// to bf16 Wt[N][K] by k_wt_all. Q is pre-scaled by 0.25*log2e (exp2-domain softmax).
// V stored as tiled V^T: [bh][kb=key/64][d=16][key%64] so attention PV fragments are
// 16B reads within a 2KB tile. Attention: barrier-free, LDS-free, split-K (2x1024),
// softmax row-sums produced by the PV MFMA itself (ones-block in A rows 16..31).

static __device__ __forceinline__ float b2f(bf16 h) { return __bfloat162float(h); }
static __device__ __forceinline__ bf16 f2b(float f) { return __float2bfloat16(f); }
static __device__ __forceinline__ unsigned short f2bu(float f) {
    bf16 h = f2b(f);
    return *reinterpret_cast<unsigned short*>(&h);
}
static __device__ __forceinline__ float bs2f(short s) {
    return __uint_as_float(((unsigned)(unsigned short)s) << 16);
}

typedef __attribute__((ext_vector_type(8))) short short8;
typedef __attribute__((ext_vector_type(4))) short short4v;
typedef __attribute__((ext_vector_type(16))) float f32x16;
typedef __attribute__((ext_vector_type(2))) int int2v;

#define QSCALE 0.36067376022224085f  // 0.25 * log2(e)

// partner-half exchange via permlane32_swap (VALU)
static __device__ __forceinline__ float xhalf(float x, int hi) {
    auto r = __builtin_amdgcn_permlane32_swap(__float_as_int(x), __float_as_int(x), false, false);
    return __int_as_float(hi ? r[0] : r[1]);
}

// ================= K0: all weight transposes+convert in one launch =================
__global__ __launch_bounds__(256) void k_wt_all(const float* __restrict__ qkv_w, const float* __restrict__ proj_w,
                                                const float* __restrict__ fc1_w, const float* __restrict__ fc2_w,
                                                bf16* __restrict__ wtq, bf16* __restrict__ wtp,
                                                bf16* __restrict__ wt1, bf16* __restrict__ wt2) {
    int idx = blockIdx.x * 256 + threadIdx.x;   // < 786432
    if (idx < 147456) {
        int b = idx / 49152, i2 = idx % 49152;
        int n = i2 >> 7, k = i2 & 127;
        wtq[idx] = f2b(qkv_w[b * 49152 + k * 384 + n]);
    } else if (idx < 196608) {
        int j = idx - 147456;
        int b = j / 16384, i2 = j % 16384;
        int n = i2 >> 7, k = i2 & 127;
        wtp[j] = f2b(proj_w[b * 16384 + k * 128 + n]);
    } else if (idx < 491520) {
        int j = idx - 196608;
        int n = j / 384, k = j - n * 384;
        wt1[j] = f2b(fc1_w[k * 768 + n]);
    } else {
        int j = idx - 491520;
        int n = j / 768, k = j - n * 768;
        wt2[j] = f2b(fc2_w[k * 384 + n]);
    }
}

// ================= shared MFMA GEMM tile: C64x64 = A[M,K] . Wt[N,K]^T =================
__device__ __forceinline__ f32x16 gemm_tile(const short* __restrict__ A, const short* __restrict__ W,
                                            int K, int rowbase, int colbase,
                                            short* als, short* wls) {
    int tid = threadIdx.x;
    int wid = tid >> 6, lane = tid & 63;
    int hi = lane >> 5, l31 = lane & 31;
    int wm = wid >> 1, wn = wid & 1;
    int sr = tid >> 3, skb = tid & 7;   // staging: row (0..31), k-block (0..7)
    f32x16 acc;
#pragma unroll
    for (int i = 0; i < 16; ++i) acc[i] = 0.f;
    for (int k0 = 0; k0 < K; k0 += 64) {
        __syncthreads();
#pragma unroll
        for (int pass = 0; pass < 2; ++pass) {
            int r = sr + pass * 32;
            short8 av = *(const short8*)&A[(size_t)(rowbase + r) * K + k0 + skb * 8];
            *(short8*)&als[r * 64 + ((skb ^ (r & 7)) * 8)] = av;
            short8 wv = *(const short8*)&W[(size_t)(colbase + r) * K + k0 + skb * 8];
            *(short8*)&wls[r * 64 + ((skb ^ (r & 7)) * 8)] = wv;
        }
        __syncthreads();
#pragma unroll
        for (int ks = 0; ks < 4; ++ks) {
            int ra = wm * 32 + l31;
            int rb = wn * 32 + l31;
            int kb = ks * 2 + hi;
            short8 af = *(const short8*)&als[ra * 64 + ((kb ^ (ra & 7)) * 8)];
            short8 bf = *(const short8*)&wls[rb * 64 + ((kb ^ (rb & 7)) * 8)];
            acc = __builtin_amdgcn_mfma_f32_32x32x16_bf16(af, bf, acc, 0, 0, 0);
        }
    }
    return acc;
}

// ================= K1: LN1 for all 3 branches =================
__global__ __launch_bounds__(256) void k_ln1(const float* __restrict__ x1, const float* __restrict__ x2,
                                             const float* __restrict__ x3, const float* __restrict__ g,
                                             const float* __restrict__ b, bf16* __restrict__ xn) {
    int tid = threadIdx.x;
    int wave = tid >> 6, lane = tid & 63;
    int grow = blockIdx.x * 4 + wave;      // 0..12287
    int branch = grow >> 12;
    const float* xp = (branch == 0) ? x1 : (branch == 1 ? x2 : x3);
    const float* row = xp + (size_t)(grow & 4095) * 128;
    float2 a = *reinterpret_cast<const float2*>(&row[2 * lane]);
    float s = a.x + a.y, sq = a.x * a.x + a.y * a.y;
#pragma unroll
    for (int off = 32; off >= 1; off >>= 1) { s += __shfl_xor(s, off); sq += __shfl_xor(sq, off); }
    float mean = s * (1.f / 128.f);
    float var = sq * (1.f / 128.f) - mean * mean;
    float rstd = rsqrtf(var + 1e-5f);
    float2 gv = *reinterpret_cast<const float2*>(&g[branch * 128 + 2 * lane]);
    float2 bv = *reinterpret_cast<const float2*>(&b[branch * 128 + 2 * lane]);
    bf16* orow = xn + (size_t)grow * 128;
    orow[2 * lane] = f2b((a.x - mean) * rstd * gv.x + bv.x);
    orow[2 * lane + 1] = f2b((a.y - mean) * rstd * gv.y + bv.y);
}

// ================= K2: QKV GEMM (MFMA); Q pre-scaled; V stored tiled-transposed =================
__global__ __launch_bounds__(256) void k_qkv_m(const bf16* __restrict__ xn, const bf16* __restrict__ wt,
                                               bf16* __restrict__ q, bf16* __restrict__ k, bf16* __restrict__ v) {
    __shared__ short als[64 * 64];
    __shared__ short wls[64 * 64];
    int branch = blockIdx.z;
    const short* A = (const short*)xn + (size_t)branch * 4096 * 128;
    const short* W = (const short*)wt + (size_t)branch * 384 * 128;
    int rowbase = blockIdx.x * 64, colbase = blockIdx.y * 64;
    f32x16 acc = gemm_tile(A, W, 128, rowbase, colbase, als, wls);
    int tid = threadIdx.x, wid = tid >> 6, lane = tid & 63;
    int hi = lane >> 5, l31 = lane & 31;
    int wm = wid >> 1, wn = wid & 1;
    int c = colbase + wn * 32 + l31;        // 0..383
    int which = c >> 7, h = (c >> 4) & 7, d = c & 15;   // which is block-uniform
    if (which < 2) {
        bf16* dst = (which == 0) ? q : k;
        float scl = (which == 0) ? QSCALE : 1.0f;
#pragma unroll
        for (int i = 0; i < 16; ++i) {
            int mrow = (i & 3) + 8 * (i >> 2) + 4 * hi;
            int token = rowbase + wm * 32 + mrow;
            int bb = token >> 11, n = token & 2047;
            dst[((((size_t)branch * 2 + bb) * 8 + h) * 2048 + n) * 16 + d] = f2b(acc[i] * scl);
        }
    } else {
        // tiled V^T: v[((bh*32 + n/64)*16 + d)*64 + n%64]
#pragma unroll
        for (int i = 0; i < 16; ++i) {
            int mrow = (i & 3) + 8 * (i >> 2) + 4 * hi;
            int token = rowbase + wm * 32 + mrow;
            int bb = token >> 11, n = token & 2047;
            size_t bh = (size_t)(branch * 2 + bb) * 8 + h;
            v[((bh * 32 + (n >> 6)) * 16 + d) * 64 + (n & 63)] = f2b(acc[i]);
        }
    }
}

// ================= K3: MFMA attention — barrier-free, LDS-free, MFMA-summed softmax =================
// 128 threads = 2 independent waves; wave owns 32 q-rows; grid (48, 32, 2) = 3072 blocks.
// PV A-operand rows 16..31 = bf16 ones -> acc[8] accumulates the per-q-row sum of P
// inside the MFMA (no VALU psum, no cross-half combine). Per-lane deferred rescale
// keyed off acc[8] exponent. Fast path: 2 QK MFMA -> 32 exp2 -> 16 cvt_pk ->
// 8 permlane -> 4 PV MFMA.
__global__ __launch_bounds__(128, 4) void k_attn(const bf16* __restrict__ qg, const bf16* __restrict__ kg,
                                                 const bf16* __restrict__ vg, bf16* __restrict__ pacc,
                                                 float2* __restrict__ psm) {
    int bh = blockIdx.x;            // (branch*2+b)*8+h
    int qblk = blockIdx.y;          // 0..31
    int split = blockIdx.z;         // 0..1
    size_t base = (size_t)bh * (2048 * 16);
    size_t vtbase = (size_t)bh * 32768;   // tiled V^T base (32 tiles x 1024)
    int tid = threadIdx.x, wave = tid >> 6, lane = tid & 63;
    int hi = lane >> 5, l31 = lane & 31;
    int qrow = qblk * 64 + wave * 32 + l31;
    const short* qs = (const short*)qg;
    const short* ks = (const short*)kg;
    const short* vts = (const short*)vg;
    short8 qf = *(const short8*)&qs[base + (size_t)qrow * 16 + hi * 8];

    short8 one8;
#pragma unroll
    for (int j = 0; j < 8; ++j) one8[j] = (short)0x3F80;   // bf16 1.0

    f32x16 acc;
    f32x16 negm;
#pragma unroll
    for (int r = 0; r < 16; ++r) { acc[r] = 0.f; negm[r] = -16.f; }
    float m = 16.f;

    int kbeg = split * 1024, kend = kbeg + 1024;

    for (int c0 = kbeg; c0 < kend; c0 += 64) {
        // deferred per-lane rescale: acc[8] is the running row-sum (from MFMA ones-block)
        if (__any(acc[8] > 2.68435456e8f)) {   // 2^28
            int e = (__float_as_int(acc[8]) >> 23) - 127;
            int shift = e > 16 ? e - 16 : 0;
            float fac = __int_as_float((127 - shift) << 23);   // 2^-shift
            m += (float)shift;
#pragma unroll
            for (int r = 0; r < 16; ++r) negm[r] = -m;
#pragma unroll
            for (int r = 0; r < 16; ++r) acc[r] *= fac;
        }
        short8 kf0 = *(const short8*)&ks[base + (size_t)(c0 + l31) * 16 + hi * 8];
        short8 kf1 = *(const short8*)&ks[base + (size_t)(c0 + 32 + l31) * 16 + hi * 8];
        short8 vf1 = one8, vf2 = one8, vf3 = one8, vf4 = one8;
        if (l31 < 16) {
            const short* vt = &vts[vtbase + (size_t)(c0 >> 6) * 1024 + l31 * 64 + hi * 8];
            vf1 = *(const short8*)&vt[0];
            vf2 = *(const short8*)&vt[16];
            vf3 = *(const short8*)&vt[32];
            vf4 = *(const short8*)&vt[48];
        }
        // QK^T with -m folded into C: output = s - m (exp2 domain)
        f32x16 pa = __builtin_amdgcn_mfma_f32_32x32x16_bf16(kf0, qf, negm, 0, 0, 0);
        f32x16 pb = __builtin_amdgcn_mfma_f32_32x32x16_bf16(kf1, qf, negm, 0, 0, 0);
#pragma unroll
        for (int r = 0; r < 16; ++r) pa[r] = __builtin_amdgcn_exp2f(pa[r]);
#pragma unroll
        for (int r = 0; r < 16; ++r) pb[r] = __builtin_amdgcn_exp2f(pb[r]);
        // P -> bf16 pairs, half-exchange via permlane32_swap
        unsigned wa[8], wb[8];
#pragma unroll
        for (int e = 0; e < 8; ++e) {
            unsigned t;
            asm("v_cvt_pk_bf16_f32 %0, %1, %2" : "=v"(t) : "v"(pa[2 * e]), "v"(pa[2 * e + 1]));
            wa[e] = t;
            asm("v_cvt_pk_bf16_f32 %0, %1, %2" : "=v"(t) : "v"(pb[2 * e]), "v"(pb[2 * e + 1]));
            wb[e] = t;
        }
        union { unsigned u[4]; short8 v; } b1, b2, b3, b4;
        {
            auto r0 = __builtin_amdgcn_permlane32_swap((int)wa[0], (int)wa[2], false, false);
            b1.u[0] = (unsigned)r0[0]; b1.u[2] = (unsigned)r0[1];
            auto r1 = __builtin_amdgcn_permlane32_swap((int)wa[1], (int)wa[3], false, false);
            b1.u[1] = (unsigned)r1[0]; b1.u[3] = (unsigned)r1[1];
            auto r2 = __builtin_amdgcn_permlane32_swap((int)wa[4], (int)wa[6], false, false);
            b2.u[0] = (unsigned)r2[0]; b2.u[2] = (unsigned)r2[1];
            auto r3 = __builtin_amdgcn_permlane32_swap((int)wa[5], (int)wa[7], false, false);
            b2.u[1] = (unsigned)r3[0]; b2.u[3] = (unsigned)r3[1];
            auto r4 = __builtin_amdgcn_permlane32_swap((int)wb[0], (int)wb[2], false, false);
            b3.u[0] = (unsigned)r4[0]; b3.u[2] = (unsigned)r4[1];
            auto r5 = __builtin_amdgcn_permlane32_swap((int)wb[1], (int)wb[3], false, false);
            b3.u[1] = (unsigned)r5[0]; b3.u[3] = (unsigned)r5[1];
            auto r6 = __builtin_amdgcn_permlane32_swap((int)wb[4], (int)wb[6], false, false);
            b4.u[0] = (unsigned)r6[0]; b4.u[2] = (unsigned)r6[1];
            auto r7 = __builtin_amdgcn_permlane32_swap((int)wb[5], (int)wb[7], false, false);
            b4.u[1] = (unsigned)r7[0]; b4.u[3] = (unsigned)r7[1];
        }
        acc = __builtin_amdgcn_mfma_f32_32x32x16_bf16(vf1, b1.v, acc, 0, 0, 0);
        acc = __builtin_amdgcn_mfma_f32_32x32x16_bf16(vf2, b2.v, acc, 0, 0, 0);
        acc = __builtin_amdgcn_mfma_f32_32x32x16_bf16(vf3, b3.v, acc, 0, 0, 0);
        acc = __builtin_amdgcn_mfma_f32_32x32x16_bf16(vf4, b4.v, acc, 0, 0, 0);
    }
    // epilogue: acc[8] = unnormalized row sum; write partials
    size_t pidx = ((size_t)(split * 48 + bh) * 2048 + qrow) * 16;
    unsigned u0 = (unsigned)f2bu(acc[0]) | ((unsigned)f2bu(acc[1]) << 16);
    unsigned u1 = (unsigned)f2bu(acc[2]) | ((unsigned)f2bu(acc[3]) << 16);
    unsigned u2 = (unsigned)f2bu(acc[4]) | ((unsigned)f2bu(acc[5]) << 16);
    unsigned u3 = (unsigned)f2bu(acc[6]) | ((unsigned)f2bu(acc[7]) << 16);
    short* pp = (short*)pacc;
    int2v w01; w01.x = (int)u0; w01.y = (int)u1;
    int2v w23; w23.x = (int)u2; w23.y = (int)u3;
    *(int2v*)&pp[pidx + 4 * hi] = w01;          // d = 4*hi .. 4*hi+3
    *(int2v*)&pp[pidx + 8 + 4 * hi] = w23;      // d = 8+4*hi .. 11+4*hi
    if (hi == 0) {
        float2 sm; sm.x = acc[8]; sm.y = m;
        psm[(size_t)(split * 48 + bh) * 2048 + qrow] = sm;
    }
}

// ================= K3b: split-K merge -> o bf16 [branch*4096+bb*2048+n][128] =================
__global__ __launch_bounds__(256) void k_attn_red(const bf16* __restrict__ pacc, const float2* __restrict__ psm,
                                                  bf16* __restrict__ o) {
    int t = blockIdx.x * 256 + threadIdx.x;    // < 196608
    int hi = t & 1;
    int qrow = (t >> 1) & 2047;
    int bh = t >> 12;
    size_t ridx = (size_t)bh * 2048 + qrow;
    float2 sm0 = psm[ridx];
    float2 sm1 = psm[(size_t)48 * 2048 + ridx];
    float mp = fmaxf(sm0.y, sm1.y);
    float w0 = __builtin_amdgcn_exp2f(sm0.y - mp);
    float w1 = __builtin_amdgcn_exp2f(sm1.y - mp);
    float inv = 1.f / (sm0.x * w0 + sm1.x * w1);
    w0 *= inv; w1 *= inv;
    const short* p0 = (const short*)pacc + ridx * 16;
    const short* p1 = (const short*)pacc + (size_t)48 * 2048 * 16 + ridx * 16;
    short4v a0 = *(const short4v*)&p0[4 * hi];
    short4v c0 = *(const short4v*)&p0[8 + 4 * hi];
    short4v a1 = *(const short4v*)&p1[4 * hi];
    short4v c1 = *(const short4v*)&p1[8 + 4 * hi];
    unsigned u0, u1, u2, u3;
    {
        float f0 = bs2f(a0[0]) * w0 + bs2f(a1[0]) * w1;
        float f1 = bs2f(a0[1]) * w0 + bs2f(a1[1]) * w1;
        float f2 = bs2f(a0[2]) * w0 + bs2f(a1[2]) * w1;
        float f3 = bs2f(a0[3]) * w0 + bs2f(a1[3]) * w1;
        u0 = (unsigned)f2bu(f0) | ((unsigned)f2bu(f1) << 16);
        u1 = (unsigned)f2bu(f2) | ((unsigned)f2bu(f3) << 16);
        float g0 = bs2f(c0[0]) * w0 + bs2f(c1[0]) * w1;
        float g1 = bs2f(c0[1]) * w0 + bs2f(c1[1]) * w1;
        float g2 = bs2f(c0[2]) * w0 + bs2f(c1[2]) * w1;
        float g3 = bs2f(c0[3]) * w0 + bs2f(c1[3]) * w1;
        u2 = (unsigned)f2bu(g0) | ((unsigned)f2bu(g1) << 16);
        u3 = (unsigned)f2bu(g2) | ((unsigned)f2bu(g3) << 16);
    }
    int branch = bh >> 4, bb = (bh >> 3) & 1, h = bh & 7;
    size_t orow = (size_t)branch * 4096 + (size_t)bb * 2048 + qrow;
    short* op = (short*)o;
    int2v w01; w01.x = (int)u0; w01.y = (int)u1;
    int2v w23; w23.x = (int)u2; w23.y = (int)u3;
    *(int2v*)&op[orow * 128 + h * 16 + 4 * hi] = w01;
    *(int2v*)&op[orow * 128 + h * 16 + 8 + 4 * hi] = w23;
}

// ================= K4: proj GEMM (MFMA) + bias + residual -> xc[4096][384] fp32 =================
__global__ __launch_bounds__(256) void k_proj_m(const bf16* __restrict__ ob, const bf16* __restrict__ wt,
                                                const float* __restrict__ pb, const float* __restrict__ x1,
                                                const float* __restrict__ x2, const float* __restrict__ x3,
                                                float* __restrict__ xc) {
    __shared__ short als[64 * 64];
    __shared__ short wls[64 * 64];
    int branch = blockIdx.z;
    const short* A = (const short*)ob + (size_t)branch * 4096 * 128;
    const short* W = (const short*)wt + (size_t)branch * 128 * 128;
    int rowbase = blockIdx.x * 64, colbase = blockIdx.y * 64;
    f32x16 acc = gemm_tile(A, W, 128, rowbase, colbase, als, wls);
    int tid = threadIdx.x, wid = tid >> 6, lane = tid & 63;
    int hi = lane >> 5, l31 = lane & 31;
    int wm = wid >> 1, wn = wid & 1;
    int c = colbase + wn * 32 + l31;        // 0..127
    float bias = pb[branch * 128 + c];
    const float* xp = (branch == 0) ? x1 : (branch == 1 ? x2 : x3);
#pragma unroll
    for (int i = 0; i < 16; ++i) {
        int mrow = (i & 3) + 8 * (i >> 2) + 4 * hi;
        int row = rowbase + wm * 32 + mrow;
        xc[(size_t)row * 384 + branch * 128 + c] = acc[i] + bias + xp[(size_t)row * 128 + c];
    }
}

// ================= K5: LN2 over 384 features =================
__global__ __launch_bounds__(256) void k_ln2(const float* __restrict__ xc, const float* __restrict__ g,
                                             const float* __restrict__ b, bf16* __restrict__ xcn) {
    int tid = threadIdx.x, wave = tid >> 6, lane = tid & 63;
    int row = blockIdx.x * 4 + wave;  // 0..4095
    const float* rp = xc + (size_t)row * 384;
    float v[6];
    float s = 0.f, sq = 0.f;
#pragma unroll
    for (int i = 0; i < 6; ++i) {
        v[i] = rp[lane + i * 64];
        s += v[i]; sq += v[i] * v[i];
    }
#pragma unroll
    for (int off = 32; off >= 1; off >>= 1) { s += __shfl_xor(s, off); sq += __shfl_xor(sq, off); }
    float mean = s * (1.f / 384.f);
    float var = sq * (1.f / 384.f) - mean * mean;
    float rstd = rsqrtf(var + 1e-5f);
    bf16* op = xcn + (size_t)row * 384;
#pragma unroll
    for (int i = 0; i < 6; ++i) {
        int c = lane + i * 64;
        op[c] = f2b((v[i] - mean) * rstd * g[c] + b[c]);
    }
}

// ================= K6: FC1 GEMM (MFMA) + bias + exact GELU -> h bf16 =================
__global__ __launch_bounds__(256) void k_fc1_m(const bf16* __restrict__ xcn, const bf16* __restrict__ wt,
                                               const float* __restrict__ bias, bf16* __restrict__ h) {
    __shared__ short als[64 * 64];
    __shared__ short wls[64 * 64];
    const short* A = (const short*)xcn;
    const short* W = (const short*)wt;
    int rowbase = blockIdx.x * 64, colbase = blockIdx.y * 64;
    f32x16 acc = gemm_tile(A, W, 384, rowbase, colbase, als, wls);
    int tid = threadIdx.x, wid = tid >> 6, lane = tid & 63;
    int hi = lane >> 5, l31 = lane & 31;
    int wm = wid >> 1, wn = wid & 1;
    int c = colbase + wn * 32 + l31;        // 0..767
    float bs = bias[c];
#pragma unroll
    for (int i = 0; i < 16; ++i) {
        int mrow = (i & 3) + 8 * (i >> 2) + 4 * hi;
        int row = rowbase + wm * 32 + mrow;
        float vv = acc[i] + bs;
        float ge = 0.5f * vv * (1.f + erff(vv * 0.70710678118f));
        h[(size_t)row * 768 + c] = f2b(ge);
    }
}

// ================= K7: FC2 GEMM (MFMA) + bias + residual -> split fp32 outputs =================
__global__ __launch_bounds__(256) void k_fc2_m(const bf16* __restrict__ h, const bf16* __restrict__ wt,
                                               const float* __restrict__ bias, const float* __restrict__ xc,
                                               float* __restrict__ outp) {
    __shared__ short als[64 * 64];
    __shared__ short wls[64 * 64];
    const short* A = (const short*)h;
    const short* W = (const short*)wt;
    int rowbase = blockIdx.x * 64, colbase = blockIdx.y * 64;
    f32x16 acc = gemm_tile(A, W, 768, rowbase, colbase, als, wls);
    int tid = threadIdx.x, wid = tid >> 6, lane = tid & 63;
    int hi = lane >> 5, l31 = lane & 31;
    int wm = wid >> 1, wn = wid & 1;
    int c = colbase + wn * 32 + l31;        // 0..383
    float bs = bias[c];
    int which = c >> 7, cc = c & 127;
#pragma unroll
    for (int i = 0; i < 16; ++i) {
        int mrow = (i & 3) + 8 * (i >> 2) + 4 * hi;
        int row = rowbase + wm * 32 + mrow;
        outp[(size_t)which * 524288 + (size_t)row * 128 + cc] = acc[i] + bs + xc[(size_t)row * 384 + c];
    }
}

// ================= launch =================
extern "C" void kernel_launch(void* const* d_in, const int* in_sizes, int n_in,
                              void* d_out, int out_size, void* d_ws, size_t ws_size,
                              hipStream_t stream) {
    const float* x1     = (const float*)d_in[0];
    const float* x2     = (const float*)d_in[1];
    const float* x3     = (const float*)d_in[2];
    const float* ln1_g  = (const float*)d_in[3];
    const float* ln1_b  = (const float*)d_in[4];
    const float* qkv_w  = (const float*)d_in[5];
    const float* proj_w = (const float*)d_in[6];
    const float* proj_b = (const float*)d_in[7];
    const float* ln2_g  = (const float*)d_in[8];
    const float* ln2_b  = (const float*)d_in[9];
    const float* fc1_w  = (const float*)d_in[10];
    const float* fc1_b  = (const float*)d_in[11];
    const float* fc2_w  = (const float*)d_in[12];
    const float* fc2_b  = (const float*)d_in[13];

    char* ws = (char*)d_ws;
    const size_t SB = 3145728;  // bf16 buffer of 1.5M elems
    bf16* xn  = (bf16*)(ws + 0 * SB);
    bf16* qb  = (bf16*)(ws + 1 * SB);
    bf16* kb  = (bf16*)(ws + 2 * SB);
    bf16* vb  = (bf16*)(ws + 3 * SB);   // tiled V^T
    bf16* ob  = (bf16*)(ws + 4 * SB);
    float* xc = (float*)(ws + 5 * SB);            // 4096*384*4 = 6291456 B
    bf16* xcn = (bf16*)(ws + 5 * SB + 6291456);   // 3145728 B
    bf16* hb  = (bf16*)(ws + 6 * SB + 6291456);   // 4096*768*2 = 6291456 B
    char* wbase = ws + 31457280;
    bf16* wtq = (bf16*)(wbase);                   // 3*384*128*2 = 294912
    bf16* wtp = (bf16*)(wbase + 294912);          // 3*128*128*2 = 98304
    bf16* wt1 = (bf16*)(wbase + 393216);          // 768*384*2   = 589824
    bf16* wt2 = (bf16*)(wbase + 983040);          // 384*768*2   = 589824
    // total = 33030144 B (~31.5 MB)
    // Split-K attention partials OVERLAY xcn+hb (both written only after attention):
    bf16*  pacc = (bf16*)(ws + 22020096);         // 2*48*2048*16*2 = 6291456 B
    float2* psm = (float2*)(ws + 28311552);       // 2*48*2048*8    = 1572864 B

    k_wt_all<<<3072, 256, 0, stream>>>(qkv_w, proj_w, fc1_w, fc2_w, wtq, wtp, wt1, wt2);
    k_ln1<<<3072, 256, 0, stream>>>(x1, x2, x3, ln1_g, ln1_b, xn);
    k_qkv_m<<<dim3(64, 6, 3), 256, 0, stream>>>(xn, wtq, qb, kb, vb);
    k_attn<<<dim3(48, 32, 2), 128, 0, stream>>>(qb, kb, vb, pacc, psm);
    k_attn_red<<<768, 256, 0, stream>>>(pacc, psm, ob);
    k_proj_m<<<dim3(64, 2, 3), 256, 0, stream>>>(ob, wtp, proj_b, x1, x2, x3, xc);
    k_ln2<<<1024, 256, 0, stream>>>(xc, ln2_g, ln2_b, xcn);
    k_fc1_m<<<dim3(64, 12, 1), 256, 0, stream>>>(xcn, wt1, fc1_b, hb);
    k_fc2_m<<<dim3(64, 6, 1), 256, 0, stream>>>(hb, wt2, fc2_b, xc, (float*)d_out);
}

// Round 13
// 95.053 us; speedup vs baseline: 1.2578x; 1.1035x over previous
//
#include <hip/hip_runtime.h>
#include <hip/hip_bf16.h>

typedef __hip_bfloat16 bf16;

// ---------- constants ----------
// B=2, N=2048, C=128, H=8, hd=16, branches=3, hid=768
// rows per branch = B*N = 4096; 3C = 384
// I/O fp32; intermediates bf16 except xc (fp32 residual). Weights pre-transposed
// to bf16 Wt[N][K] (fused into k_pre). Q pre-scaled by 0.25*log2e (exp2-domain).
// V stored as tiled V^T: [bh][kb=key/64][d=16][key%64]. Attention: barrier-free,
// LDS-free, split-K (2x1024), R10-exact loop (guarded rescale kept — empirically
// load-bearing: R11/R12 removal attempts both miscompiled/failed). Split-K merge
// is fused into k_proj_m's A-staging (bit-identical math to the old k_attn_red).

static __device__ __forceinline__ float b2f(bf16 h) { return __bfloat162float(h); }
static __device__ __forceinline__ bf16 f2b(float f) { return __float2bfloat16(f); }
static __device__ __forceinline__ unsigned short f2bu(float f) {
    bf16 h = f2b(f);
    return *reinterpret_cast<unsigned short*>(&h);
}
static __device__ __forceinline__ float bs2f(short s) {
    return __uint_as_float(((unsigned)(unsigned short)s) << 16);
}

typedef __attribute__((ext_vector_type(8))) short short8;
typedef __attribute__((ext_vector_type(4))) short short4v;
typedef __attribute__((ext_vector_type(16))) float f32x16;
typedef __attribute__((ext_vector_type(2))) int int2v;

#define QSCALE 0.36067376022224085f  // 0.25 * log2(e)

// partner-half exchange via permlane32_swap (VALU)
static __device__ __forceinline__ float xhalf(float x, int hi) {
    auto r = __builtin_amdgcn_permlane32_swap(__float_as_int(x), __float_as_int(x), false, false);
    return __int_as_float(hi ? r[0] : r[1]);
}

// ================= K0: fused weight transpose+convert AND LN1 =================
// blocks [3072..6143]: weight transposes (idx = (bid-3072)*256+tid, < 786432)
// blocks [0..3071]:    LN1 for all 3 branches (one wave per row)
__global__ __launch_bounds__(256) void k_pre(const float* __restrict__ x1, const float* __restrict__ x2,
                                             const float* __restrict__ x3, const float* __restrict__ g,
                                             const float* __restrict__ b, bf16* __restrict__ xn,
                                             const float* __restrict__ qkv_w, const float* __restrict__ proj_w,
                                             const float* __restrict__ fc1_w, const float* __restrict__ fc2_w,
                                             bf16* __restrict__ wtq, bf16* __restrict__ wtp,
                                             bf16* __restrict__ wt1, bf16* __restrict__ wt2) {
    if (blockIdx.x >= 3072) {
        int idx = (blockIdx.x - 3072) * 256 + threadIdx.x;   // < 786432
        if (idx < 147456) {
            int bq = idx / 49152, i2 = idx % 49152;
            int n = i2 >> 7, k = i2 & 127;
            wtq[idx] = f2b(qkv_w[bq * 49152 + k * 384 + n]);
        } else if (idx < 196608) {
            int j = idx - 147456;
            int bq = j / 16384, i2 = j % 16384;
            int n = i2 >> 7, k = i2 & 127;
            wtp[j] = f2b(proj_w[bq * 16384 + k * 128 + n]);
        } else if (idx < 491520) {
            int j = idx - 196608;
            int n = j / 384, k = j - n * 384;
            wt1[j] = f2b(fc1_w[k * 768 + n]);
        } else {
            int j = idx - 491520;
            int n = j / 768, k = j - n * 768;
            wt2[j] = f2b(fc2_w[k * 384 + n]);
        }
        return;
    }
    int tid = threadIdx.x;
    int wave = tid >> 6, lane = tid & 63;
    int grow = blockIdx.x * 4 + wave;      // 0..12287
    int branch = grow >> 12;
    const float* xp = (branch == 0) ? x1 : (branch == 1 ? x2 : x3);
    const float* row = xp + (size_t)(grow & 4095) * 128;
    float2 a = *reinterpret_cast<const float2*>(&row[2 * lane]);
    float s = a.x + a.y, sq = a.x * a.x + a.y * a.y;
#pragma unroll
    for (int off = 32; off >= 1; off >>= 1) { s += __shfl_xor(s, off); sq += __shfl_xor(sq, off); }
    float mean = s * (1.f / 128.f);
    float var = sq * (1.f / 128.f) - mean * mean;
    float rstd = rsqrtf(var + 1e-5f);
    float2 gv = *reinterpret_cast<const float2*>(&g[branch * 128 + 2 * lane]);
    float2 bv = *reinterpret_cast<const float2*>(&b[branch * 128 + 2 * lane]);
    bf16* orow = xn + (size_t)grow * 128;
    orow[2 * lane] = f2b((a.x - mean) * rstd * gv.x + bv.x);
    orow[2 * lane + 1] = f2b((a.y - mean) * rstd * gv.y + bv.y);
}

// ================= shared MFMA GEMM tile: C64x64 = A[M,K] . Wt[N,K]^T =================
__device__ __forceinline__ f32x16 gemm_tile(const short* __restrict__ A, const short* __restrict__ W,
                                            int K, int rowbase, int colbase,
                                            short* als, short* wls) {
    int tid = threadIdx.x;
    int wid = tid >> 6, lane = tid & 63;
    int hi = lane >> 5, l31 = lane & 31;
    int wm = wid >> 1, wn = wid & 1;
    int sr = tid >> 3, skb = tid & 7;   // staging: row (0..31), k-block (0..7)
    f32x16 acc;
#pragma unroll
    for (int i = 0; i < 16; ++i) acc[i] = 0.f;
    for (int k0 = 0; k0 < K; k0 += 64) {
        __syncthreads();
#pragma unroll
        for (int pass = 0; pass < 2; ++pass) {
            int r = sr + pass * 32;
            short8 av = *(const short8*)&A[(size_t)(rowbase + r) * K + k0 + skb * 8];
            *(short8*)&als[r * 64 + ((skb ^ (r & 7)) * 8)] = av;
            short8 wv = *(const short8*)&W[(size_t)(colbase + r) * K + k0 + skb * 8];
            *(short8*)&wls[r * 64 + ((skb ^ (r & 7)) * 8)] = wv;
        }
        __syncthreads();
#pragma unroll
        for (int ks = 0; ks < 4; ++ks) {
            int ra = wm * 32 + l31;
            int rb = wn * 32 + l31;
            int kb = ks * 2 + hi;
            short8 af = *(const short8*)&als[ra * 64 + ((kb ^ (ra & 7)) * 8)];
            short8 bf = *(const short8*)&wls[rb * 64 + ((kb ^ (rb & 7)) * 8)];
            acc = __builtin_amdgcn_mfma_f32_32x32x16_bf16(af, bf, acc, 0, 0, 0);
        }
    }
    return acc;
}

// ================= K2: QKV GEMM (MFMA); Q pre-scaled; V stored tiled-transposed =================
__global__ __launch_bounds__(256) void k_qkv_m(const bf16* __restrict__ xn, const bf16* __restrict__ wt,
                                               bf16* __restrict__ q, bf16* __restrict__ k, bf16* __restrict__ v) {
    __shared__ short als[64 * 64];
    __shared__ short wls[64 * 64];
    int branch = blockIdx.z;
    const short* A = (const short*)xn + (size_t)branch * 4096 * 128;
    const short* W = (const short*)wt + (size_t)branch * 384 * 128;
    int rowbase = blockIdx.x * 64, colbase = blockIdx.y * 64;
    f32x16 acc = gemm_tile(A, W, 128, rowbase, colbase, als, wls);
    int tid = threadIdx.x, wid = tid >> 6, lane = tid & 63;
    int hi = lane >> 5, l31 = lane & 31;
    int wm = wid >> 1, wn = wid & 1;
    int c = colbase + wn * 32 + l31;        // 0..383
    int which = c >> 7, h = (c >> 4) & 7, d = c & 15;   // which is block-uniform
    if (which < 2) {
        bf16* dst = (which == 0) ? q : k;
        float scl = (which == 0) ? QSCALE : 1.0f;
#pragma unroll
        for (int i = 0; i < 16; ++i) {
            int mrow = (i & 3) + 8 * (i >> 2) + 4 * hi;
            int token = rowbase + wm * 32 + mrow;
            int bb = token >> 11, n = token & 2047;
            dst[((((size_t)branch * 2 + bb) * 8 + h) * 2048 + n) * 16 + d] = f2b(acc[i] * scl);
        }
    } else {
        // tiled V^T: v[((bh*32 + n/64)*16 + d)*64 + n%64]
#pragma unroll
        for (int i = 0; i < 16; ++i) {
            int mrow = (i & 3) + 8 * (i >> 2) + 4 * hi;
            int token = rowbase + wm * 32 + mrow;
            int bb = token >> 11, n = token & 2047;
            size_t bh = (size_t)(branch * 2 + bb) * 8 + h;
            v[((bh * 32 + (n >> 6)) * 16 + d) * 64 + (n & 63)] = f2b(acc[i]);
        }
    }
}

// ================= K3: MFMA attention — EXACT R10 (proven pass) =================
// 128 threads = 2 independent waves; wave owns 32 q-rows; grid (48, 32, 2) = 3072 blocks.
// Guarded per-lane deferred rescale kept — removing it (R11/R12) broke correctness.
__global__ __launch_bounds__(128, 4) void k_attn(const bf16* __restrict__ qg, const bf16* __restrict__ kg,
                                                 const bf16* __restrict__ vg, bf16* __restrict__ pacc,
                                                 float2* __restrict__ psm) {
    int bh = blockIdx.x;            // (branch*2+b)*8+h
    int qblk = blockIdx.y;          // 0..31
    int split = blockIdx.z;         // 0..1
    size_t base = (size_t)bh * (2048 * 16);
    size_t vtbase = (size_t)bh * 32768;   // tiled V^T base (32 tiles x 1024)
    int tid = threadIdx.x, wave = tid >> 6, lane = tid & 63;
    int hi = lane >> 5, l31 = lane & 31;
    int qrow = qblk * 64 + wave * 32 + l31;
    const short* qs = (const short*)qg;
    const short* ks = (const short*)kg;
    const short* vts = (const short*)vg;
    short8 qf = *(const short8*)&qs[base + (size_t)qrow * 16 + hi * 8];

    short8 one8;
#pragma unroll
    for (int j = 0; j < 8; ++j) one8[j] = (short)0x3F80;   // bf16 1.0

    f32x16 acc;
    f32x16 negm;
#pragma unroll
    for (int r = 0; r < 16; ++r) { acc[r] = 0.f; negm[r] = -16.f; }
    float m = 16.f;

    int kbeg = split * 1024, kend = kbeg + 1024;

    for (int c0 = kbeg; c0 < kend; c0 += 64) {
        // deferred per-lane rescale: acc[8] is the running row-sum (from MFMA ones-block)
        if (__any(acc[8] > 2.68435456e8f)) {   // 2^28
            int e = (__float_as_int(acc[8]) >> 23) - 127;
            int shift = e > 16 ? e - 16 : 0;
            float fac = __int_as_float((127 - shift) << 23);   // 2^-shift
            m += (float)shift;
#pragma unroll
            for (int r = 0; r < 16; ++r) negm[r] = -m;
#pragma unroll
            for (int r = 0; r < 16; ++r) acc[r] *= fac;
        }
        short8 kf0 = *(const short8*)&ks[base + (size_t)(c0 + l31) * 16 + hi * 8];
        short8 kf1 = *(const short8*)&ks[base + (size_t)(c0 + 32 + l31) * 16 + hi * 8];
        short8 vf1 = one8, vf2 = one8, vf3 = one8, vf4 = one8;
        if (l31 < 16) {
            const short* vt = &vts[vtbase + (size_t)(c0 >> 6) * 1024 + l31 * 64 + hi * 8];
            vf1 = *(const short8*)&vt[0];
            vf2 = *(const short8*)&vt[16];
            vf3 = *(const short8*)&vt[32];
            vf4 = *(const short8*)&vt[48];
        }
        // QK^T with -m folded into C: output = s - m (exp2 domain)
        f32x16 pa = __builtin_amdgcn_mfma_f32_32x32x16_bf16(kf0, qf, negm, 0, 0, 0);
        f32x16 pb = __builtin_amdgcn_mfma_f32_32x32x16_bf16(kf1, qf, negm, 0, 0, 0);
#pragma unroll
        for (int r = 0; r < 16; ++r) pa[r] = __builtin_amdgcn_exp2f(pa[r]);
#pragma unroll
        for (int r = 0; r < 16; ++r) pb[r] = __builtin_amdgcn_exp2f(pb[r]);
        // P -> bf16 pairs, half-exchange via permlane32_swap
        unsigned wa[8], wb[8];
#pragma unroll
        for (int e = 0; e < 8; ++e) {
            unsigned t;
            asm("v_cvt_pk_bf16_f32 %0, %1, %2" : "=v"(t) : "v"(pa[2 * e]), "v"(pa[2 * e + 1]));
            wa[e] = t;
            asm("v_cvt_pk_bf16_f32 %0, %1, %2" : "=v"(t) : "v"(pb[2 * e]), "v"(pb[2 * e + 1]));
            wb[e] = t;
        }
        union { unsigned u[4]; short8 v; } b1, b2, b3, b4;
        {
            auto r0 = __builtin_amdgcn_permlane32_swap((int)wa[0], (int)wa[2], false, false);
            b1.u[0] = (unsigned)r0[0]; b1.u[2] = (unsigned)r0[1];
            auto r1 = __builtin_amdgcn_permlane32_swap((int)wa[1], (int)wa[3], false, false);
            b1.u[1] = (unsigned)r1[0]; b1.u[3] = (unsigned)r1[1];
            auto r2 = __builtin_amdgcn_permlane32_swap((int)wa[4], (int)wa[6], false, false);
            b2.u[0] = (unsigned)r2[0]; b2.u[2] = (unsigned)r2[1];
            auto r3 = __builtin_amdgcn_permlane32_swap((int)wa[5], (int)wa[7], false, false);
            b2.u[1] = (unsigned)r3[0]; b2.u[3] = (unsigned)r3[1];
            auto r4 = __builtin_amdgcn_permlane32_swap((int)wb[0], (int)wb[2], false, false);
            b3.u[0] = (unsigned)r4[0]; b3.u[2] = (unsigned)r4[1];
            auto r5 = __builtin_amdgcn_permlane32_swap((int)wb[1], (int)wb[3], false, false);
            b3.u[1] = (unsigned)r5[0]; b3.u[3] = (unsigned)r5[1];
            auto r6 = __builtin_amdgcn_permlane32_swap((int)wb[4], (int)wb[6], false, false);
            b4.u[0] = (unsigned)r6[0]; b4.u[2] = (unsigned)r6[1];
            auto r7 = __builtin_amdgcn_permlane32_swap((int)wb[5], (int)wb[7], false, false);
            b4.u[1] = (unsigned)r7[0]; b4.u[3] = (unsigned)r7[1];
        }
        acc = __builtin_amdgcn_mfma_f32_32x32x16_bf16(vf1, b1.v, acc, 0, 0, 0);
        acc = __builtin_amdgcn_mfma_f32_32x32x16_bf16(vf2, b2.v, acc, 0, 0, 0);
        acc = __builtin_amdgcn_mfma_f32_32x32x16_bf16(vf3, b3.v, acc, 0, 0, 0);
        acc = __builtin_amdgcn_mfma_f32_32x32x16_bf16(vf4, b4.v, acc, 0, 0, 0);
    }
    // epilogue: acc[8] = unnormalized row sum; write partials
    size_t pidx = ((size_t)(split * 48 + bh) * 2048 + qrow) * 16;
    unsigned u0 = (unsigned)f2bu(acc[0]) | ((unsigned)f2bu(acc[1]) << 16);
    unsigned u1 = (unsigned)f2bu(acc[2]) | ((unsigned)f2bu(acc[3]) << 16);
    unsigned u2 = (unsigned)f2bu(acc[4]) | ((unsigned)f2bu(acc[5]) << 16);
    unsigned u3 = (unsigned)f2bu(acc[6]) | ((unsigned)f2bu(acc[7]) << 16);
    short* pp = (short*)pacc;
    int2v w01; w01.x = (int)u0; w01.y = (int)u1;
    int2v w23; w23.x = (int)u2; w23.y = (int)u3;
    *(int2v*)&pp[pidx + 4 * hi] = w01;          // d = 4*hi .. 4*hi+3
    *(int2v*)&pp[pidx + 8 + 4 * hi] = w23;      // d = 8+4*hi .. 11+4*hi
    if (hi == 0) {
        float2 sm; sm.x = acc[8]; sm.y = m;
        psm[(size_t)(split * 48 + bh) * 2048 + qrow] = sm;
    }
}

// ================= K4: proj GEMM with FUSED split-K merge in A-staging =================
// A[row][c] (c = h*16+d) is computed on the fly from pacc/psm (bit-identical to the
// old k_attn_red output) while staging into LDS. B = wtp. Epilogue: bias + residual.
__global__ __launch_bounds__(256) void k_proj_m(const bf16* __restrict__ pacc, const float2* __restrict__ psm,
                                                const bf16* __restrict__ wt, const float* __restrict__ pb,
                                                const float* __restrict__ x1, const float* __restrict__ x2,
                                                const float* __restrict__ x3, float* __restrict__ xc) {
    __shared__ short als[64 * 64];
    __shared__ short wls[64 * 64];
    int branch = blockIdx.z;
    const short* W = (const short*)wt + (size_t)branch * 128 * 128;
    const short* pp = (const short*)pacc;
    int rowbase = blockIdx.x * 64, colbase = blockIdx.y * 64;
    int tid = threadIdx.x;
    int wid = tid >> 6, lane = tid & 63;
    int hi = lane >> 5, l31 = lane & 31;
    int wm = wid >> 1, wn = wid & 1;
    int sr = tid >> 3, skb = tid & 7;
    f32x16 acc;
#pragma unroll
    for (int i = 0; i < 16; ++i) acc[i] = 0.f;
    for (int k0 = 0; k0 < 128; k0 += 64) {
        __syncthreads();
#pragma unroll
        for (int pass = 0; pass < 2; ++pass) {
            int r = sr + pass * 32;
            int row = rowbase + r;                  // token row within branch
            int bb = row >> 11, n = row & 2047;
            int h = (k0 >> 4) + (skb >> 1);         // head for these 8 cols
            int dlo = (skb & 1) * 8;                // d offset (0 or 8)
            size_t bh = (size_t)(branch * 2 + bb) * 8 + h;
            size_t ridx = bh * 2048 + n;
            float2 sm0 = psm[ridx];
            float2 sm1 = psm[(size_t)48 * 2048 + ridx];
            float mp = fmaxf(sm0.y, sm1.y);
            float w0 = __builtin_amdgcn_exp2f(sm0.y - mp);
            float w1 = __builtin_amdgcn_exp2f(sm1.y - mp);
            float inv = 1.f / (sm0.x * w0 + sm1.x * w1);
            w0 *= inv; w1 *= inv;
            short8 a0 = *(const short8*)&pp[ridx * 16 + dlo];
            short8 a1 = *(const short8*)&pp[((size_t)48 * 2048 + ridx) * 16 + dlo];
            short8 av;
#pragma unroll
            for (int j = 0; j < 8; ++j)
                av[j] = (short)f2bu(bs2f(a0[j]) * w0 + bs2f(a1[j]) * w1);
            *(short8*)&als[r * 64 + ((skb ^ (r & 7)) * 8)] = av;
            short8 wv = *(const short8*)&W[(size_t)(colbase + r) * 128 + k0 + skb * 8];
            *(short8*)&wls[r * 64 + ((skb ^ (r & 7)) * 8)] = wv;
        }
        __syncthreads();
#pragma unroll
        for (int ks = 0; ks < 4; ++ks) {
            int ra = wm * 32 + l31;
            int rb = wn * 32 + l31;
            int kb = ks * 2 + hi;
            short8 af = *(const short8*)&als[ra * 64 + ((kb ^ (ra & 7)) * 8)];
            short8 bf = *(const short8*)&wls[rb * 64 + ((kb ^ (rb & 7)) * 8)];
            acc = __builtin_amdgcn_mfma_f32_32x32x16_bf16(af, bf, acc, 0, 0, 0);
        }
    }
    int c = colbase + wn * 32 + l31;        // 0..127
    float bias = pb[branch * 128 + c];
    const float* xp = (branch == 0) ? x1 : (branch == 1 ? x2 : x3);
#pragma unroll
    for (int i = 0; i < 16; ++i) {
        int mrow = (i & 3) + 8 * (i >> 2) + 4 * hi;
        int row = rowbase + wm * 32 + mrow;
        xc[(size_t)row * 384 + branch * 128 + c] = acc[i] + bias + xp[(size_t)row * 128 + c];
    }
}

// ================= K5: LN2 over 384 features =================
__global__ __launch_bounds__(256) void k_ln2(const float* __restrict__ xc, const float* __restrict__ g,
                                             const float* __restrict__ b, bf16* __restrict__ xcn) {
    int tid = threadIdx.x, wave = tid >> 6, lane = tid & 63;
    int row = blockIdx.x * 4 + wave;  // 0..4095
    const float* rp = xc + (size_t)row * 384;
    float v[6];
    float s = 0.f, sq = 0.f;
#pragma unroll
    for (int i = 0; i < 6; ++i) {
        v[i] = rp[lane + i * 64];
        s += v[i]; sq += v[i] * v[i];
    }
#pragma unroll
    for (int off = 32; off >= 1; off >>= 1) { s += __shfl_xor(s, off); sq += __shfl_xor(sq, off); }
    float mean = s * (1.f / 384.f);
    float var = sq * (1.f / 384.f) - mean * mean;
    float rstd = rsqrtf(var + 1e-5f);
    bf16* op = xcn + (size_t)row * 384;
#pragma unroll
    for (int i = 0; i < 6; ++i) {
        int c = lane + i * 64;
        op[c] = f2b((v[i] - mean) * rstd * g[c] + b[c]);
    }
}

// ================= K6: FC1 GEMM (MFMA) + bias + exact GELU -> h bf16 =================
__global__ __launch_bounds__(256) void k_fc1_m(const bf16* __restrict__ xcn, const bf16* __restrict__ wt,
                                               const float* __restrict__ bias, bf16* __restrict__ h) {
    __shared__ short als[64 * 64];
    __shared__ short wls[64 * 64];
    const short* A = (const short*)xcn;
    const short* W = (const short*)wt;
    int rowbase = blockIdx.x * 64, colbase = blockIdx.y * 64;
    f32x16 acc = gemm_tile(A, W, 384, rowbase, colbase, als, wls);
    int tid = threadIdx.x, wid = tid >> 6, lane = tid & 63;
    int hi = lane >> 5, l31 = lane & 31;
    int wm = wid >> 1, wn = wid & 1;
    int c = colbase + wn * 32 + l31;        // 0..767
    float bs = bias[c];
#pragma unroll
    for (int i = 0; i < 16; ++i) {
        int mrow = (i & 3) + 8 * (i >> 2) + 4 * hi;
        int row = rowbase + wm * 32 + mrow;
        float vv = acc[i] + bs;
        float ge = 0.5f * vv * (1.f + erff(vv * 0.70710678118f));
        h[(size_t)row * 768 + c] = f2b(ge);
    }
}

// ================= K7: FC2 GEMM (MFMA) + bias + residual -> split fp32 outputs =================
__global__ __launch_bounds__(256) void k_fc2_m(const bf16* __restrict__ h, const bf16* __restrict__ wt,
                                               const float* __restrict__ bias, const float* __restrict__ xc,
                                               float* __restrict__ outp) {
    __shared__ short als[64 * 64];
    __shared__ short wls[64 * 64];
    const short* A = (const short*)h;
    const short* W = (const short*)wt;
    int rowbase = blockIdx.x * 64, colbase = blockIdx.y * 64;
    f32x16 acc = gemm_tile(A, W, 768, rowbase, colbase, als, wls);
    int tid = threadIdx.x, wid = tid >> 6, lane = tid & 63;
    int hi = lane >> 5, l31 = lane & 31;
    int wm = wid >> 1, wn = wid & 1;
    int c = colbase + wn * 32 + l31;        // 0..383
    float bs = bias[c];
    int which = c >> 7, cc = c & 127;
#pragma unroll
    for (int i = 0; i < 16; ++i) {
        int mrow = (i & 3) + 8 * (i >> 2) + 4 * hi;
        int row = rowbase + wm * 32 + mrow;
        outp[(size_t)which * 524288 + (size_t)row * 128 + cc] = acc[i] + bs + xc[(size_t)row * 384 + c];
    }
}

// ================= launch =================
extern "C" void kernel_launch(void* const* d_in, const int* in_sizes, int n_in,
                              void* d_out, int out_size, void* d_ws, size_t ws_size,
                              hipStream_t stream) {
    const float* x1     = (const float*)d_in[0];
    const float* x2     = (const float*)d_in[1];
    const float* x3     = (const float*)d_in[2];
    const float* ln1_g  = (const float*)d_in[3];
    const float* ln1_b  = (const float*)d_in[4];
    const float* qkv_w  = (const float*)d_in[5];
    const float* proj_w = (const float*)d_in[6];
    const float* proj_b = (const float*)d_in[7];
    const float* ln2_g  = (const float*)d_in[8];
    const float* ln2_b  = (const float*)d_in[9];
    const float* fc1_w  = (const float*)d_in[10];
    const float* fc1_b  = (const float*)d_in[11];
    const float* fc2_w  = (const float*)d_in[12];
    const float* fc2_b  = (const float*)d_in[13];

    char* ws = (char*)d_ws;
    const size_t SB = 3145728;  // bf16 buffer of 1.5M elems
    bf16* xn  = (bf16*)(ws + 0 * SB);
    bf16* qb  = (bf16*)(ws + 1 * SB);
    bf16* kb  = (bf16*)(ws + 2 * SB);
    bf16* vb  = (bf16*)(ws + 3 * SB);   // tiled V^T
    float* xc = (float*)(ws + 5 * SB);            // 4096*384*4 = 6291456 B
    bf16* xcn = (bf16*)(ws + 5 * SB + 6291456);   // 3145728 B
    bf16* hb  = (bf16*)(ws + 6 * SB + 6291456);   // 4096*768*2 = 6291456 B
    char* wbase = ws + 31457280;
    bf16* wtq = (bf16*)(wbase);                   // 3*384*128*2 = 294912
    bf16* wtp = (bf16*)(wbase + 294912);          // 3*128*128*2 = 98304
    bf16* wt1 = (bf16*)(wbase + 393216);          // 768*384*2   = 589824
    bf16* wt2 = (bf16*)(wbase + 983040);          // 384*768*2   = 589824
    // total = 33030144 B (~31.5 MB)
    // Split-K attention partials OVERLAY xcn+hb (both written only after proj reads them):
    bf16*  pacc = (bf16*)(ws + 22020096);         // 2*48*2048*16*2 = 6291456 B
    float2* psm = (float2*)(ws + 28311552);       // 2*48*2048*8    = 1572864 B

    k_pre<<<6144, 256, 0, stream>>>(x1, x2, x3, ln1_g, ln1_b, xn,
                                    qkv_w, proj_w, fc1_w, fc2_w, wtq, wtp, wt1, wt2);
    k_qkv_m<<<dim3(64, 6, 3), 256, 0, stream>>>(xn, wtq, qb, kb, vb);
    k_attn<<<dim3(48, 32, 2), 128, 0, stream>>>(qb, kb, vb, pacc, psm);
    k_proj_m<<<dim3(64, 2, 3), 256, 0, stream>>>(pacc, psm, wtp, proj_b, x1, x2, x3, xc);
    k_ln2<<<1024, 256, 0, stream>>>(xc, ln2_g, ln2_b, xcn);
    k_fc1_m<<<dim3(64, 12, 1), 256, 0, stream>>>(xcn, wt1, fc1_b, hb);
    k_fc2_m<<<dim3(64, 6, 1), 256, 0, stream>>>(hb, wt2, fc2_b, xc, (float*)d_out);
}

// Round 14
// 84.799 us; speedup vs baseline: 1.4099x; 1.1209x over previous
//
#include <hip/hip_runtime.h>
#include <hip/hip_bf16.h>

typedef __hip_bfloat16 bf16;

// ---------- constants ----------
// B=2, N=2048, C=128, H=8, hd=16, branches=3, hid=768
// rows per branch = B*N = 4096; 3C = 384
// I/O fp32; intermediates bf16 except xc (fp32 residual). Weights pre-transposed
// to bf16 Wt[N][K] (fused into k_pre). Q pre-scaled by 0.25*log2e (exp2-domain).
// V stored as tiled V^T: [bh][kb=key/64][d=16][key%64]. Attention: barrier-free,
// LDS-free, split-K (2x1024), R10-exact per-stream loop (guarded rescale kept),
// TWO Q-tiles per wave sharing K/V loads (ILP). Split-K merge fused into k_proj_m.

static __device__ __forceinline__ float b2f(bf16 h) { return __bfloat162float(h); }
static __device__ __forceinline__ bf16 f2b(float f) { return __float2bfloat16(f); }
static __device__ __forceinline__ unsigned short f2bu(float f) {
    bf16 h = f2b(f);
    return *reinterpret_cast<unsigned short*>(&h);
}
static __device__ __forceinline__ float bs2f(short s) {
    return __uint_as_float(((unsigned)(unsigned short)s) << 16);
}

typedef __attribute__((ext_vector_type(8))) short short8;
typedef __attribute__((ext_vector_type(4))) short short4v;
typedef __attribute__((ext_vector_type(16))) float f32x16;
typedef __attribute__((ext_vector_type(2))) int int2v;

#define QSCALE 0.36067376022224085f  // 0.25 * log2(e)

// ================= K0: fused weight transpose+convert AND LN1 =================
__global__ __launch_bounds__(256) void k_pre(const float* __restrict__ x1, const float* __restrict__ x2,
                                             const float* __restrict__ x3, const float* __restrict__ g,
                                             const float* __restrict__ b, bf16* __restrict__ xn,
                                             const float* __restrict__ qkv_w, const float* __restrict__ proj_w,
                                             const float* __restrict__ fc1_w, const float* __restrict__ fc2_w,
                                             bf16* __restrict__ wtq, bf16* __restrict__ wtp,
                                             bf16* __restrict__ wt1, bf16* __restrict__ wt2) {
    if (blockIdx.x >= 3072) {
        int idx = (blockIdx.x - 3072) * 256 + threadIdx.x;   // < 786432
        if (idx < 147456) {
            int bq = idx / 49152, i2 = idx % 49152;
            int n = i2 >> 7, k = i2 & 127;
            wtq[idx] = f2b(qkv_w[bq * 49152 + k * 384 + n]);
        } else if (idx < 196608) {
            int j = idx - 147456;
            int bq = j / 16384, i2 = j % 16384;
            int n = i2 >> 7, k = i2 & 127;
            wtp[j] = f2b(proj_w[bq * 16384 + k * 128 + n]);
        } else if (idx < 491520) {
            int j = idx - 196608;
            int n = j / 384, k = j - n * 384;
            wt1[j] = f2b(fc1_w[k * 768 + n]);
        } else {
            int j = idx - 491520;
            int n = j / 768, k = j - n * 768;
            wt2[j] = f2b(fc2_w[k * 384 + n]);
        }
        return;
    }
    int tid = threadIdx.x;
    int wave = tid >> 6, lane = tid & 63;
    int grow = blockIdx.x * 4 + wave;      // 0..12287
    int branch = grow >> 12;
    const float* xp = (branch == 0) ? x1 : (branch == 1 ? x2 : x3);
    const float* row = xp + (size_t)(grow & 4095) * 128;
    float2 a = *reinterpret_cast<const float2*>(&row[2 * lane]);
    float s = a.x + a.y, sq = a.x * a.x + a.y * a.y;
#pragma unroll
    for (int off = 32; off >= 1; off >>= 1) { s += __shfl_xor(s, off); sq += __shfl_xor(sq, off); }
    float mean = s * (1.f / 128.f);
    float var = sq * (1.f / 128.f) - mean * mean;
    float rstd = rsqrtf(var + 1e-5f);
    float2 gv = *reinterpret_cast<const float2*>(&g[branch * 128 + 2 * lane]);
    float2 bv = *reinterpret_cast<const float2*>(&b[branch * 128 + 2 * lane]);
    bf16* orow = xn + (size_t)grow * 128;
    orow[2 * lane] = f2b((a.x - mean) * rstd * gv.x + bv.x);
    orow[2 * lane + 1] = f2b((a.y - mean) * rstd * gv.y + bv.y);
}

// ================= shared MFMA GEMM tile: C64x64 = A[M,K] . Wt[N,K]^T =================
__device__ __forceinline__ f32x16 gemm_tile(const short* __restrict__ A, const short* __restrict__ W,
                                            int K, int rowbase, int colbase,
                                            short* als, short* wls) {
    int tid = threadIdx.x;
    int wid = tid >> 6, lane = tid & 63;
    int hi = lane >> 5, l31 = lane & 31;
    int wm = wid >> 1, wn = wid & 1;
    int sr = tid >> 3, skb = tid & 7;   // staging: row (0..31), k-block (0..7)
    f32x16 acc;
#pragma unroll
    for (int i = 0; i < 16; ++i) acc[i] = 0.f;
    for (int k0 = 0; k0 < K; k0 += 64) {
        __syncthreads();
#pragma unroll
        for (int pass = 0; pass < 2; ++pass) {
            int r = sr + pass * 32;
            short8 av = *(const short8*)&A[(size_t)(rowbase + r) * K + k0 + skb * 8];
            *(short8*)&als[r * 64 + ((skb ^ (r & 7)) * 8)] = av;
            short8 wv = *(const short8*)&W[(size_t)(colbase + r) * K + k0 + skb * 8];
            *(short8*)&wls[r * 64 + ((skb ^ (r & 7)) * 8)] = wv;
        }
        __syncthreads();
#pragma unroll
        for (int ks = 0; ks < 4; ++ks) {
            int ra = wm * 32 + l31;
            int rb = wn * 32 + l31;
            int kb = ks * 2 + hi;
            short8 af = *(const short8*)&als[ra * 64 + ((kb ^ (ra & 7)) * 8)];
            short8 bf = *(const short8*)&wls[rb * 64 + ((kb ^ (rb & 7)) * 8)];
            acc = __builtin_amdgcn_mfma_f32_32x32x16_bf16(af, bf, acc, 0, 0, 0);
        }
    }
    return acc;
}

// ================= K2: QKV GEMM (MFMA); Q pre-scaled; V stored tiled-transposed =================
__global__ __launch_bounds__(256) void k_qkv_m(const bf16* __restrict__ xn, const bf16* __restrict__ wt,
                                               bf16* __restrict__ q, bf16* __restrict__ k, bf16* __restrict__ v) {
    __shared__ short als[64 * 64];
    __shared__ short wls[64 * 64];
    int branch = blockIdx.z;
    const short* A = (const short*)xn + (size_t)branch * 4096 * 128;
    const short* W = (const short*)wt + (size_t)branch * 384 * 128;
    int rowbase = blockIdx.x * 64, colbase = blockIdx.y * 64;
    f32x16 acc = gemm_tile(A, W, 128, rowbase, colbase, als, wls);
    int tid = threadIdx.x, wid = tid >> 6, lane = tid & 63;
    int hi = lane >> 5, l31 = lane & 31;
    int wm = wid >> 1, wn = wid & 1;
    int c = colbase + wn * 32 + l31;        // 0..383
    int which = c >> 7, h = (c >> 4) & 7, d = c & 15;   // which is block-uniform
    if (which < 2) {
        bf16* dst = (which == 0) ? q : k;
        float scl = (which == 0) ? QSCALE : 1.0f;
#pragma unroll
        for (int i = 0; i < 16; ++i) {
            int mrow = (i & 3) + 8 * (i >> 2) + 4 * hi;
            int token = rowbase + wm * 32 + mrow;
            int bb = token >> 11, n = token & 2047;
            dst[((((size_t)branch * 2 + bb) * 8 + h) * 2048 + n) * 16 + d] = f2b(acc[i] * scl);
        }
    } else {
        // tiled V^T: v[((bh*32 + n/64)*16 + d)*64 + n%64]
#pragma unroll
        for (int i = 0; i < 16; ++i) {
            int mrow = (i & 3) + 8 * (i >> 2) + 4 * hi;
            int token = rowbase + wm * 32 + mrow;
            int bb = token >> 11, n = token & 2047;
            size_t bh = (size_t)(branch * 2 + bb) * 8 + h;
            v[((bh * 32 + (n >> 6)) * 16 + d) * 64 + (n & 63)] = f2b(acc[i]);
        }
    }
}

// ---- one attention stream: QK (C=-m) -> exp2 -> cvt_pk -> permlane -> 4 PV into acc ----
static __device__ __forceinline__ void attn_stream(short8 kf0, short8 kf1,
                                                   short8 vf1, short8 vf2, short8 vf3, short8 vf4,
                                                   short8 qf, const f32x16& negm, f32x16& acc) {
    f32x16 pa = __builtin_amdgcn_mfma_f32_32x32x16_bf16(kf0, qf, negm, 0, 0, 0);
    f32x16 pb = __builtin_amdgcn_mfma_f32_32x32x16_bf16(kf1, qf, negm, 0, 0, 0);
#pragma unroll
    for (int r = 0; r < 16; ++r) pa[r] = __builtin_amdgcn_exp2f(pa[r]);
#pragma unroll
    for (int r = 0; r < 16; ++r) pb[r] = __builtin_amdgcn_exp2f(pb[r]);
    unsigned wa[8], wb[8];
#pragma unroll
    for (int e = 0; e < 8; ++e) {
        unsigned t;
        asm("v_cvt_pk_bf16_f32 %0, %1, %2" : "=v"(t) : "v"(pa[2 * e]), "v"(pa[2 * e + 1]));
        wa[e] = t;
        asm("v_cvt_pk_bf16_f32 %0, %1, %2" : "=v"(t) : "v"(pb[2 * e]), "v"(pb[2 * e + 1]));
        wb[e] = t;
    }
    union { unsigned u[4]; short8 v; } b1, b2, b3, b4;
    {
        auto r0 = __builtin_amdgcn_permlane32_swap((int)wa[0], (int)wa[2], false, false);
        b1.u[0] = (unsigned)r0[0]; b1.u[2] = (unsigned)r0[1];
        auto r1 = __builtin_amdgcn_permlane32_swap((int)wa[1], (int)wa[3], false, false);
        b1.u[1] = (unsigned)r1[0]; b1.u[3] = (unsigned)r1[1];
        auto r2 = __builtin_amdgcn_permlane32_swap((int)wa[4], (int)wa[6], false, false);
        b2.u[0] = (unsigned)r2[0]; b2.u[2] = (unsigned)r2[1];
        auto r3 = __builtin_amdgcn_permlane32_swap((int)wa[5], (int)wa[7], false, false);
        b2.u[1] = (unsigned)r3[0]; b2.u[3] = (unsigned)r3[1];
        auto r4 = __builtin_amdgcn_permlane32_swap((int)wb[0], (int)wb[2], false, false);
        b3.u[0] = (unsigned)r4[0]; b3.u[2] = (unsigned)r4[1];
        auto r5 = __builtin_amdgcn_permlane32_swap((int)wb[1], (int)wb[3], false, false);
        b3.u[1] = (unsigned)r5[0]; b3.u[3] = (unsigned)r5[1];
        auto r6 = __builtin_amdgcn_permlane32_swap((int)wb[4], (int)wb[6], false, false);
        b4.u[0] = (unsigned)r6[0]; b4.u[2] = (unsigned)r6[1];
        auto r7 = __builtin_amdgcn_permlane32_swap((int)wb[5], (int)wb[7], false, false);
        b4.u[1] = (unsigned)r7[0]; b4.u[3] = (unsigned)r7[1];
    }
    acc = __builtin_amdgcn_mfma_f32_32x32x16_bf16(vf1, b1.v, acc, 0, 0, 0);
    acc = __builtin_amdgcn_mfma_f32_32x32x16_bf16(vf2, b2.v, acc, 0, 0, 0);
    acc = __builtin_amdgcn_mfma_f32_32x32x16_bf16(vf3, b3.v, acc, 0, 0, 0);
    acc = __builtin_amdgcn_mfma_f32_32x32x16_bf16(vf4, b4.v, acc, 0, 0, 0);
}

// ================= K3: MFMA attention — 2 Q-tiles per wave, shared K/V =================
// grid (48 bh, 16, 2 split), 128 threads = 2 waves. Wave handles Q-tiles qblk and
// qblk+16 (32 rows each) with shared K/V loads. Per-stream loop body is R10-exact,
// including the guarded loop-carried rescale (load-bearing per R11/R12).
__global__ __launch_bounds__(128, 2) void k_attn(const bf16* __restrict__ qg, const bf16* __restrict__ kg,
                                                 const bf16* __restrict__ vg, bf16* __restrict__ pacc,
                                                 float2* __restrict__ psm) {
    int bh = blockIdx.x;            // (branch*2+b)*8+h
    int qblk = blockIdx.y;          // 0..15 (tile B = qblk+16)
    int split = blockIdx.z;         // 0..1
    size_t base = (size_t)bh * (2048 * 16);
    size_t vtbase = (size_t)bh * 32768;   // tiled V^T base (32 tiles x 1024)
    int tid = threadIdx.x, wave = tid >> 6, lane = tid & 63;
    int hi = lane >> 5, l31 = lane & 31;
    int qrowA = qblk * 64 + wave * 32 + l31;
    int qrowB = (qblk + 16) * 64 + wave * 32 + l31;
    const short* qs = (const short*)qg;
    const short* ks = (const short*)kg;
    const short* vts = (const short*)vg;
    short8 qfA = *(const short8*)&qs[base + (size_t)qrowA * 16 + hi * 8];
    short8 qfB = *(const short8*)&qs[base + (size_t)qrowB * 16 + hi * 8];

    short8 one8;
#pragma unroll
    for (int j = 0; j < 8; ++j) one8[j] = (short)0x3F80;   // bf16 1.0

    f32x16 accA, accB, negmA, negmB;
#pragma unroll
    for (int r = 0; r < 16; ++r) { accA[r] = 0.f; accB[r] = 0.f; negmA[r] = -16.f; negmB[r] = -16.f; }
    float mA = 16.f, mB = 16.f;

    int kbeg = split * 1024, kend = kbeg + 1024;

    for (int c0 = kbeg; c0 < kend; c0 += 64) {
        // guarded per-lane deferred rescale per stream (loop-carried read of acc[8])
        if (__any(accA[8] > 2.68435456e8f)) {   // 2^28
            int e = (__float_as_int(accA[8]) >> 23) - 127;
            int shift = e > 16 ? e - 16 : 0;
            float fac = __int_as_float((127 - shift) << 23);   // 2^-shift
            mA += (float)shift;
#pragma unroll
            for (int r = 0; r < 16; ++r) negmA[r] = -mA;
#pragma unroll
            for (int r = 0; r < 16; ++r) accA[r] *= fac;
        }
        if (__any(accB[8] > 2.68435456e8f)) {
            int e = (__float_as_int(accB[8]) >> 23) - 127;
            int shift = e > 16 ? e - 16 : 0;
            float fac = __int_as_float((127 - shift) << 23);
            mB += (float)shift;
#pragma unroll
            for (int r = 0; r < 16; ++r) negmB[r] = -mB;
#pragma unroll
            for (int r = 0; r < 16; ++r) accB[r] *= fac;
        }
        short8 kf0 = *(const short8*)&ks[base + (size_t)(c0 + l31) * 16 + hi * 8];
        short8 kf1 = *(const short8*)&ks[base + (size_t)(c0 + 32 + l31) * 16 + hi * 8];
        short8 vf1 = one8, vf2 = one8, vf3 = one8, vf4 = one8;
        if (l31 < 16) {
            const short* vt = &vts[vtbase + (size_t)(c0 >> 6) * 1024 + l31 * 64 + hi * 8];
            vf1 = *(const short8*)&vt[0];
            vf2 = *(const short8*)&vt[16];
            vf3 = *(const short8*)&vt[32];
            vf4 = *(const short8*)&vt[48];
        }
        attn_stream(kf0, kf1, vf1, vf2, vf3, vf4, qfA, negmA, accA);
        attn_stream(kf0, kf1, vf1, vf2, vf3, vf4, qfB, negmB, accB);
    }
    // epilogue: acc[8] = unnormalized row sum; write both partials
    short* pp = (short*)pacc;
    {
        size_t pidx = ((size_t)(split * 48 + bh) * 2048 + qrowA) * 16;
        unsigned u0 = (unsigned)f2bu(accA[0]) | ((unsigned)f2bu(accA[1]) << 16);
        unsigned u1 = (unsigned)f2bu(accA[2]) | ((unsigned)f2bu(accA[3]) << 16);
        unsigned u2 = (unsigned)f2bu(accA[4]) | ((unsigned)f2bu(accA[5]) << 16);
        unsigned u3 = (unsigned)f2bu(accA[6]) | ((unsigned)f2bu(accA[7]) << 16);
        int2v w01; w01.x = (int)u0; w01.y = (int)u1;
        int2v w23; w23.x = (int)u2; w23.y = (int)u3;
        *(int2v*)&pp[pidx + 4 * hi] = w01;
        *(int2v*)&pp[pidx + 8 + 4 * hi] = w23;
        if (hi == 0) {
            float2 sm; sm.x = accA[8]; sm.y = mA;
            psm[(size_t)(split * 48 + bh) * 2048 + qrowA] = sm;
        }
    }
    {
        size_t pidx = ((size_t)(split * 48 + bh) * 2048 + qrowB) * 16;
        unsigned u0 = (unsigned)f2bu(accB[0]) | ((unsigned)f2bu(accB[1]) << 16);
        unsigned u1 = (unsigned)f2bu(accB[2]) | ((unsigned)f2bu(accB[3]) << 16);
        unsigned u2 = (unsigned)f2bu(accB[4]) | ((unsigned)f2bu(accB[5]) << 16);
        unsigned u3 = (unsigned)f2bu(accB[6]) | ((unsigned)f2bu(accB[7]) << 16);
        int2v w01; w01.x = (int)u0; w01.y = (int)u1;
        int2v w23; w23.x = (int)u2; w23.y = (int)u3;
        *(int2v*)&pp[pidx + 4 * hi] = w01;
        *(int2v*)&pp[pidx + 8 + 4 * hi] = w23;
        if (hi == 0) {
            float2 sm; sm.x = accB[8]; sm.y = mB;
            psm[(size_t)(split * 48 + bh) * 2048 + qrowB] = sm;
        }
    }
}

// ================= K4: proj GEMM with FUSED split-K merge in A-staging =================
__global__ __launch_bounds__(256) void k_proj_m(const bf16* __restrict__ pacc, const float2* __restrict__ psm,
                                                const bf16* __restrict__ wt, const float* __restrict__ pb,
                                                const float* __restrict__ x1, const float* __restrict__ x2,
                                                const float* __restrict__ x3, float* __restrict__ xc) {
    __shared__ short als[64 * 64];
    __shared__ short wls[64 * 64];
    int branch = blockIdx.z;
    const short* W = (const short*)wt + (size_t)branch * 128 * 128;
    const short* pp = (const short*)pacc;
    int rowbase = blockIdx.x * 64, colbase = blockIdx.y * 64;
    int tid = threadIdx.x;
    int wid = tid >> 6, lane = tid & 63;
    int hi = lane >> 5, l31 = lane & 31;
    int wm = wid >> 1, wn = wid & 1;
    int sr = tid >> 3, skb = tid & 7;
    f32x16 acc;
#pragma unroll
    for (int i = 0; i < 16; ++i) acc[i] = 0.f;
    for (int k0 = 0; k0 < 128; k0 += 64) {
        __syncthreads();
#pragma unroll
        for (int pass = 0; pass < 2; ++pass) {
            int r = sr + pass * 32;
            int row = rowbase + r;                  // token row within branch
            int bb = row >> 11, n = row & 2047;
            int h = (k0 >> 4) + (skb >> 1);         // head for these 8 cols
            int dlo = (skb & 1) * 8;                // d offset (0 or 8)
            size_t bh = (size_t)(branch * 2 + bb) * 8 + h;
            size_t ridx = bh * 2048 + n;
            float2 sm0 = psm[ridx];
            float2 sm1 = psm[(size_t)48 * 2048 + ridx];
            float mp = fmaxf(sm0.y, sm1.y);
            float w0 = __builtin_amdgcn_exp2f(sm0.y - mp);
            float w1 = __builtin_amdgcn_exp2f(sm1.y - mp);
            float inv = 1.f / (sm0.x * w0 + sm1.x * w1);
            w0 *= inv; w1 *= inv;
            short8 a0 = *(const short8*)&pp[ridx * 16 + dlo];
            short8 a1 = *(const short8*)&pp[((size_t)48 * 2048 + ridx) * 16 + dlo];
            short8 av;
#pragma unroll
            for (int j = 0; j < 8; ++j)
                av[j] = (short)f2bu(bs2f(a0[j]) * w0 + bs2f(a1[j]) * w1);
            *(short8*)&als[r * 64 + ((skb ^ (r & 7)) * 8)] = av;
            short8 wv = *(const short8*)&W[(size_t)(colbase + r) * 128 + k0 + skb * 8];
            *(short8*)&wls[r * 64 + ((skb ^ (r & 7)) * 8)] = wv;
        }
        __syncthreads();
#pragma unroll
        for (int ks = 0; ks < 4; ++ks) {
            int ra = wm * 32 + l31;
            int rb = wn * 32 + l31;
            int kb = ks * 2 + hi;
            short8 af = *(const short8*)&als[ra * 64 + ((kb ^ (ra & 7)) * 8)];
            short8 bf = *(const short8*)&wls[rb * 64 + ((kb ^ (rb & 7)) * 8)];
            acc = __builtin_amdgcn_mfma_f32_32x32x16_bf16(af, bf, acc, 0, 0, 0);
        }
    }
    int c = colbase + wn * 32 + l31;        // 0..127
    float bias = pb[branch * 128 + c];
    const float* xp = (branch == 0) ? x1 : (branch == 1 ? x2 : x3);
#pragma unroll
    for (int i = 0; i < 16; ++i) {
        int mrow = (i & 3) + 8 * (i >> 2) + 4 * hi;
        int row = rowbase + wm * 32 + mrow;
        xc[(size_t)row * 384 + branch * 128 + c] = acc[i] + bias + xp[(size_t)row * 128 + c];
    }
}

// ================= K5: LN2 over 384 features =================
__global__ __launch_bounds__(256) void k_ln2(const float* __restrict__ xc, const float* __restrict__ g,
                                             const float* __restrict__ b, bf16* __restrict__ xcn) {
    int tid = threadIdx.x, wave = tid >> 6, lane = tid & 63;
    int row = blockIdx.x * 4 + wave;  // 0..4095
    const float* rp = xc + (size_t)row * 384;
    float v[6];
    float s = 0.f, sq = 0.f;
#pragma unroll
    for (int i = 0; i < 6; ++i) {
        v[i] = rp[lane + i * 64];
        s += v[i]; sq += v[i] * v[i];
    }
#pragma unroll
    for (int off = 32; off >= 1; off >>= 1) { s += __shfl_xor(s, off); sq += __shfl_xor(sq, off); }
    float mean = s * (1.f / 384.f);
    float var = sq * (1.f / 384.f) - mean * mean;
    float rstd = rsqrtf(var + 1e-5f);
    bf16* op = xcn + (size_t)row * 384;
#pragma unroll
    for (int i = 0; i < 6; ++i) {
        int c = lane + i * 64;
        op[c] = f2b((v[i] - mean) * rstd * g[c] + b[c]);
    }
}

// ================= K6: FC1 GEMM (MFMA) + bias + exact GELU -> h bf16 =================
__global__ __launch_bounds__(256) void k_fc1_m(const bf16* __restrict__ xcn, const bf16* __restrict__ wt,
                                               const float* __restrict__ bias, bf16* __restrict__ h) {
    __shared__ short als[64 * 64];
    __shared__ short wls[64 * 64];
    const short* A = (const short*)xcn;
    const short* W = (const short*)wt;
    int rowbase = blockIdx.x * 64, colbase = blockIdx.y * 64;
    f32x16 acc = gemm_tile(A, W, 384, rowbase, colbase, als, wls);
    int tid = threadIdx.x, wid = tid >> 6, lane = tid & 63;
    int hi = lane >> 5, l31 = lane & 31;
    int wm = wid >> 1, wn = wid & 1;
    int c = colbase + wn * 32 + l31;        // 0..767
    float bs = bias[c];
#pragma unroll
    for (int i = 0; i < 16; ++i) {
        int mrow = (i & 3) + 8 * (i >> 2) + 4 * hi;
        int row = rowbase + wm * 32 + mrow;
        float vv = acc[i] + bs;
        float ge = 0.5f * vv * (1.f + erff(vv * 0.70710678118f));
        h[(size_t)row * 768 + c] = f2b(ge);
    }
}

// ================= K7: FC2 GEMM (MFMA) + bias + residual -> split fp32 outputs =================
__global__ __launch_bounds__(256) void k_fc2_m(const bf16* __restrict__ h, const bf16* __restrict__ wt,
                                               const float* __restrict__ bias, const float* __restrict__ xc,
                                               float* __restrict__ outp) {
    __shared__ short als[64 * 64];
    __shared__ short wls[64 * 64];
    const short* A = (const short*)h;
    const short* W = (const short*)wt;
    int rowbase = blockIdx.x * 64, colbase = blockIdx.y * 64;
    f32x16 acc = gemm_tile(A, W, 768, rowbase, colbase, als, wls);
    int tid = threadIdx.x, wid = tid >> 6, lane = tid & 63;
    int hi = lane >> 5, l31 = lane & 31;
    int wm = wid >> 1, wn = wid & 1;
    int c = colbase + wn * 32 + l31;        // 0..383
    float bs = bias[c];
    int which = c >> 7, cc = c & 127;
#pragma unroll
    for (int i = 0; i < 16; ++i) {
        int mrow = (i & 3) + 8 * (i >> 2) + 4 * hi;
        int row = rowbase + wm * 32 + mrow;
        outp[(size_t)which * 524288 + (size_t)row * 128 + cc] = acc[i] + bs + xc[(size_t)row * 384 + c];
    }
}

// ================= launch =================
extern "C" void kernel_launch(void* const* d_in, const int* in_sizes, int n_in,
                              void* d_out, int out_size, void* d_ws, size_t ws_size,
                              hipStream_t stream) {
    const float* x1     = (const float*)d_in[0];
    const float* x2     = (const float*)d_in[1];
    const float* x3     = (const float*)d_in[2];
    const float* ln1_g  = (const float*)d_in[3];
    const float* ln1_b  = (const float*)d_in[4];
    const float* qkv_w  = (const float*)d_in[5];
    const float* proj_w = (const float*)d_in[6];
    const float* proj_b = (const float*)d_in[7];
    const float* ln2_g  = (const float*)d_in[8];
    const float* ln2_b  = (const float*)d_in[9];
    const float* fc1_w  = (const float*)d_in[10];
    const float* fc1_b  = (const float*)d_in[11];
    const float* fc2_w  = (const float*)d_in[12];
    const float* fc2_b  = (const float*)d_in[13];

    char* ws = (char*)d_ws;
    const size_t SB = 3145728;  // bf16 buffer of 1.5M elems
    bf16* xn  = (bf16*)(ws + 0 * SB);
    bf16* qb  = (bf16*)(ws + 1 * SB);
    bf16* kb  = (bf16*)(ws + 2 * SB);
    bf16* vb  = (bf16*)(ws + 3 * SB);   // tiled V^T
    float* xc = (float*)(ws + 5 * SB);            // 4096*384*4 = 6291456 B
    bf16* xcn = (bf16*)(ws + 5 * SB + 6291456);   // 3145728 B
    bf16* hb  = (bf16*)(ws + 6 * SB + 6291456);   // 4096*768*2 = 6291456 B
    char* wbase = ws + 31457280;
    bf16* wtq = (bf16*)(wbase);                   // 3*384*128*2 = 294912
    bf16* wtp = (bf16*)(wbase + 294912);          // 3*128*128*2 = 98304
    bf16* wt1 = (bf16*)(wbase + 393216);          // 768*384*2   = 589824
    bf16* wt2 = (bf16*)(wbase + 983040);          // 384*768*2   = 589824
    // total = 33030144 B (~31.5 MB)
    // Split-K attention partials OVERLAY xcn+hb (both written only after proj reads them):
    bf16*  pacc = (bf16*)(ws + 22020096);         // 2*48*2048*16*2 = 6291456 B
    float2* psm = (float2*)(ws + 28311552);       // 2*48*2048*8    = 1572864 B

    k_pre<<<6144, 256, 0, stream>>>(x1, x2, x3, ln1_g, ln1_b, xn,
                                    qkv_w, proj_w, fc1_w, fc2_w, wtq, wtp, wt1, wt2);
    k_qkv_m<<<dim3(64, 6, 3), 256, 0, stream>>>(xn, wtq, qb, kb, vb);
    k_attn<<<dim3(48, 16, 2), 128, 0, stream>>>(qb, kb, vb, pacc, psm);
    k_proj_m<<<dim3(64, 2, 3), 256, 0, stream>>>(pacc, psm, wtp, proj_b, x1, x2, x3, xc);
    k_ln2<<<1024, 256, 0, stream>>>(xc, ln2_g, ln2_b, xcn);
    k_fc1_m<<<dim3(64, 12, 1), 256, 0, stream>>>(xcn, wt1, fc1_b, hb);
    k_fc2_m<<<dim3(64, 6, 1), 256, 0, stream>>>(hb, wt2, fc2_b, xc, (float*)d_out);
}

// Round 15
// 84.688 us; speedup vs baseline: 1.4117x; 1.0013x over previous
//
#include <hip/hip_runtime.h>
#include <hip/hip_bf16.h>

typedef __hip_bfloat16 bf16;

// ---------- constants ----------
// B=2, N=2048, C=128, H=8, hd=16, branches=3, hid=768
// rows per branch = B*N = 4096; 3C = 384
// I/O fp32; intermediates bf16 except xc (fp32 residual). Weights pre-transposed
// to bf16 Wt[N][K] (fused into k_pre). Q pre-scaled by 0.25*log2e (exp2-domain).
// V stored as tiled V^T: [bh][kb=key/64][d=16][key%64]. Attention: barrier-free,
// LDS-free, split-K (2x1024), R10-exact per-stream loop (guarded rescale kept),
// two Q-tiles per wave. qkv/fc1 GEMMs use 64x128 tiles (2 accs, shared A-tile);
// proj/fc2 keep the proven 64x64 tile. Split-K merge fused into k_proj_m.

static __device__ __forceinline__ float b2f(bf16 h) { return __bfloat162float(h); }
static __device__ __forceinline__ bf16 f2b(float f) { return __float2bfloat16(f); }
static __device__ __forceinline__ unsigned short f2bu(float f) {
    bf16 h = f2b(f);
    return *reinterpret_cast<unsigned short*>(&h);
}
static __device__ __forceinline__ float bs2f(short s) {
    return __uint_as_float(((unsigned)(unsigned short)s) << 16);
}

typedef __attribute__((ext_vector_type(8))) short short8;
typedef __attribute__((ext_vector_type(4))) short short4v;
typedef __attribute__((ext_vector_type(16))) float f32x16;
typedef __attribute__((ext_vector_type(2))) int int2v;

#define QSCALE 0.36067376022224085f  // 0.25 * log2(e)

// ================= K0: fused weight transpose+convert AND LN1 =================
__global__ __launch_bounds__(256) void k_pre(const float* __restrict__ x1, const float* __restrict__ x2,
                                             const float* __restrict__ x3, const float* __restrict__ g,
                                             const float* __restrict__ b, bf16* __restrict__ xn,
                                             const float* __restrict__ qkv_w, const float* __restrict__ proj_w,
                                             const float* __restrict__ fc1_w, const float* __restrict__ fc2_w,
                                             bf16* __restrict__ wtq, bf16* __restrict__ wtp,
                                             bf16* __restrict__ wt1, bf16* __restrict__ wt2) {
    if (blockIdx.x >= 3072) {
        int idx = (blockIdx.x - 3072) * 256 + threadIdx.x;   // < 786432
        if (idx < 147456) {
            int bq = idx / 49152, i2 = idx % 49152;
            int n = i2 >> 7, k = i2 & 127;
            wtq[idx] = f2b(qkv_w[bq * 49152 + k * 384 + n]);
        } else if (idx < 196608) {
            int j = idx - 147456;
            int bq = j / 16384, i2 = j % 16384;
            int n = i2 >> 7, k = i2 & 127;
            wtp[j] = f2b(proj_w[bq * 16384 + k * 128 + n]);
        } else if (idx < 491520) {
            int j = idx - 196608;
            int n = j / 384, k = j - n * 384;
            wt1[j] = f2b(fc1_w[k * 768 + n]);
        } else {
            int j = idx - 491520;
            int n = j / 768, k = j - n * 768;
            wt2[j] = f2b(fc2_w[k * 384 + n]);
        }
        return;
    }
    int tid = threadIdx.x;
    int wave = tid >> 6, lane = tid & 63;
    int grow = blockIdx.x * 4 + wave;      // 0..12287
    int branch = grow >> 12;
    const float* xp = (branch == 0) ? x1 : (branch == 1 ? x2 : x3);
    const float* row = xp + (size_t)(grow & 4095) * 128;
    float2 a = *reinterpret_cast<const float2*>(&row[2 * lane]);
    float s = a.x + a.y, sq = a.x * a.x + a.y * a.y;
#pragma unroll
    for (int off = 32; off >= 1; off >>= 1) { s += __shfl_xor(s, off); sq += __shfl_xor(sq, off); }
    float mean = s * (1.f / 128.f);
    float var = sq * (1.f / 128.f) - mean * mean;
    float rstd = rsqrtf(var + 1e-5f);
    float2 gv = *reinterpret_cast<const float2*>(&g[branch * 128 + 2 * lane]);
    float2 bv = *reinterpret_cast<const float2*>(&b[branch * 128 + 2 * lane]);
    bf16* orow = xn + (size_t)grow * 128;
    orow[2 * lane] = f2b((a.x - mean) * rstd * gv.x + bv.x);
    orow[2 * lane + 1] = f2b((a.y - mean) * rstd * gv.y + bv.y);
}

// ================= shared MFMA GEMM tile: C64x64 = A[M,K] . Wt[N,K]^T =================
__device__ __forceinline__ f32x16 gemm_tile(const short* __restrict__ A, const short* __restrict__ W,
                                            int K, int rowbase, int colbase,
                                            short* als, short* wls) {
    int tid = threadIdx.x;
    int wid = tid >> 6, lane = tid & 63;
    int hi = lane >> 5, l31 = lane & 31;
    int wm = wid >> 1, wn = wid & 1;
    int sr = tid >> 3, skb = tid & 7;   // staging: row (0..31), k-block (0..7)
    f32x16 acc;
#pragma unroll
    for (int i = 0; i < 16; ++i) acc[i] = 0.f;
    for (int k0 = 0; k0 < K; k0 += 64) {
        __syncthreads();
#pragma unroll
        for (int pass = 0; pass < 2; ++pass) {
            int r = sr + pass * 32;
            short8 av = *(const short8*)&A[(size_t)(rowbase + r) * K + k0 + skb * 8];
            *(short8*)&als[r * 64 + ((skb ^ (r & 7)) * 8)] = av;
            short8 wv = *(const short8*)&W[(size_t)(colbase + r) * K + k0 + skb * 8];
            *(short8*)&wls[r * 64 + ((skb ^ (r & 7)) * 8)] = wv;
        }
        __syncthreads();
#pragma unroll
        for (int ks = 0; ks < 4; ++ks) {
            int ra = wm * 32 + l31;
            int rb = wn * 32 + l31;
            int kb = ks * 2 + hi;
            short8 af = *(const short8*)&als[ra * 64 + ((kb ^ (ra & 7)) * 8)];
            short8 bf = *(const short8*)&wls[rb * 64 + ((kb ^ (rb & 7)) * 8)];
            acc = __builtin_amdgcn_mfma_f32_32x32x16_bf16(af, bf, acc, 0, 0, 0);
        }
    }
    return acc;
}

// ================= wide MFMA GEMM tile: C64x128 = A[M,K] . Wt[N,K]^T (2 accs) =================
// A-tile staged once, W-tile 128 rows; wave (wm,wn) covers rows wm*32, cols wn*64 + {0,32}.
__device__ __forceinline__ void gemm_tile2(const short* __restrict__ A, const short* __restrict__ W,
                                           int K, int rowbase, int colbase,
                                           short* als, short* wls, f32x16& acc0, f32x16& acc1) {
    int tid = threadIdx.x;
    int wid = tid >> 6, lane = tid & 63;
    int hi = lane >> 5, l31 = lane & 31;
    int wm = wid >> 1, wn = wid & 1;
    int sr = tid >> 3, skb = tid & 7;
#pragma unroll
    for (int i = 0; i < 16; ++i) { acc0[i] = 0.f; acc1[i] = 0.f; }
    for (int k0 = 0; k0 < K; k0 += 64) {
        __syncthreads();
#pragma unroll
        for (int pass = 0; pass < 2; ++pass) {
            int r = sr + pass * 32;
            short8 av = *(const short8*)&A[(size_t)(rowbase + r) * K + k0 + skb * 8];
            *(short8*)&als[r * 64 + ((skb ^ (r & 7)) * 8)] = av;
        }
#pragma unroll
        for (int pass = 0; pass < 4; ++pass) {
            int r = sr + pass * 32;   // 0..127 (W rows = output cols)
            short8 wv = *(const short8*)&W[(size_t)(colbase + r) * K + k0 + skb * 8];
            *(short8*)&wls[r * 64 + ((skb ^ (r & 7)) * 8)] = wv;
        }
        __syncthreads();
#pragma unroll
        for (int ks = 0; ks < 4; ++ks) {
            int ra = wm * 32 + l31;
            int rb0 = wn * 64 + l31;
            int rb1 = wn * 64 + 32 + l31;
            int kb = ks * 2 + hi;
            short8 af = *(const short8*)&als[ra * 64 + ((kb ^ (ra & 7)) * 8)];
            short8 bf0 = *(const short8*)&wls[rb0 * 64 + ((kb ^ (rb0 & 7)) * 8)];
            short8 bf1 = *(const short8*)&wls[rb1 * 64 + ((kb ^ (rb1 & 7)) * 8)];
            acc0 = __builtin_amdgcn_mfma_f32_32x32x16_bf16(af, bf0, acc0, 0, 0, 0);
            acc1 = __builtin_amdgcn_mfma_f32_32x32x16_bf16(af, bf1, acc1, 0, 0, 0);
        }
    }
}

// ================= K2: QKV GEMM (64x128 tile); Q pre-scaled; V tiled-transposed =================
// grid (64, 3, 3): blockIdx.y selects the 128-col slab = exactly one of {q,k,v}.
__global__ __launch_bounds__(256) void k_qkv_m(const bf16* __restrict__ xn, const bf16* __restrict__ wt,
                                               bf16* __restrict__ q, bf16* __restrict__ k, bf16* __restrict__ v) {
    __shared__ short als[64 * 64];     // 8 KB
    __shared__ short wls[128 * 64];    // 16 KB
    int branch = blockIdx.z;
    const short* A = (const short*)xn + (size_t)branch * 4096 * 128;
    const short* W = (const short*)wt + (size_t)branch * 384 * 128;
    int rowbase = blockIdx.x * 64, colbase = blockIdx.y * 128;
    f32x16 acc0, acc1;
    gemm_tile2(A, W, 128, rowbase, colbase, als, wls, acc0, acc1);
    int tid = threadIdx.x, wid = tid >> 6, lane = tid & 63;
    int hi = lane >> 5, l31 = lane & 31;
    int wm = wid >> 1, wn = wid & 1;
    int which = blockIdx.y;                 // 0=q, 1=k, 2=v (block-uniform)
    int c0 = wn * 64 + l31;                 // 0..127 within slab
    int c1 = c0 + 32;
    if (which < 2) {
        bf16* dst = (which == 0) ? q : k;
        float scl = (which == 0) ? QSCALE : 1.0f;
        int h0 = c0 >> 4, d0 = c0 & 15;
        int h1 = c1 >> 4, d1 = c1 & 15;
#pragma unroll
        for (int i = 0; i < 16; ++i) {
            int mrow = (i & 3) + 8 * (i >> 2) + 4 * hi;
            int token = rowbase + wm * 32 + mrow;
            int bb = token >> 11, n = token & 2047;
            size_t rowb = (((size_t)branch * 2 + bb) * 8);
            dst[((rowb + h0) * 2048 + n) * 16 + d0] = f2b(acc0[i] * scl);
            dst[((rowb + h1) * 2048 + n) * 16 + d1] = f2b(acc1[i] * scl);
        }
    } else {
        int h0 = c0 >> 4, d0 = c0 & 15;
        int h1 = c1 >> 4, d1 = c1 & 15;
#pragma unroll
        for (int i = 0; i < 16; ++i) {
            int mrow = (i & 3) + 8 * (i >> 2) + 4 * hi;
            int token = rowbase + wm * 32 + mrow;
            int bb = token >> 11, n = token & 2047;
            size_t bhb = ((size_t)(branch * 2 + bb) * 8);
            v[(((bhb + h0) * 32 + (n >> 6)) * 16 + d0) * 64 + (n & 63)] = f2b(acc0[i]);
            v[(((bhb + h1) * 32 + (n >> 6)) * 16 + d1) * 64 + (n & 63)] = f2b(acc1[i]);
        }
    }
}

// ---- one attention stream: QK (C=-m) -> exp2 -> cvt_pk -> permlane -> 4 PV into acc ----
static __device__ __forceinline__ void attn_stream(short8 kf0, short8 kf1,
                                                   short8 vf1, short8 vf2, short8 vf3, short8 vf4,
                                                   short8 qf, const f32x16& negm, f32x16& acc) {
    f32x16 pa = __builtin_amdgcn_mfma_f32_32x32x16_bf16(kf0, qf, negm, 0, 0, 0);
    f32x16 pb = __builtin_amdgcn_mfma_f32_32x32x16_bf16(kf1, qf, negm, 0, 0, 0);
#pragma unroll
    for (int r = 0; r < 16; ++r) pa[r] = __builtin_amdgcn_exp2f(pa[r]);
#pragma unroll
    for (int r = 0; r < 16; ++r) pb[r] = __builtin_amdgcn_exp2f(pb[r]);
    unsigned wa[8], wb[8];
#pragma unroll
    for (int e = 0; e < 8; ++e) {
        unsigned t;
        asm("v_cvt_pk_bf16_f32 %0, %1, %2" : "=v"(t) : "v"(pa[2 * e]), "v"(pa[2 * e + 1]));
        wa[e] = t;
        asm("v_cvt_pk_bf16_f32 %0, %1, %2" : "=v"(t) : "v"(pb[2 * e]), "v"(pb[2 * e + 1]));
        wb[e] = t;
    }
    union { unsigned u[4]; short8 v; } b1, b2, b3, b4;
    {
        auto r0 = __builtin_amdgcn_permlane32_swap((int)wa[0], (int)wa[2], false, false);
        b1.u[0] = (unsigned)r0[0]; b1.u[2] = (unsigned)r0[1];
        auto r1 = __builtin_amdgcn_permlane32_swap((int)wa[1], (int)wa[3], false, false);
        b1.u[1] = (unsigned)r1[0]; b1.u[3] = (unsigned)r1[1];
        auto r2 = __builtin_amdgcn_permlane32_swap((int)wa[4], (int)wa[6], false, false);
        b2.u[0] = (unsigned)r2[0]; b2.u[2] = (unsigned)r2[1];
        auto r3 = __builtin_amdgcn_permlane32_swap((int)wa[5], (int)wa[7], false, false);
        b2.u[1] = (unsigned)r3[0]; b2.u[3] = (unsigned)r3[1];
        auto r4 = __builtin_amdgcn_permlane32_swap((int)wb[0], (int)wb[2], false, false);
        b3.u[0] = (unsigned)r4[0]; b3.u[2] = (unsigned)r4[1];
        auto r5 = __builtin_amdgcn_permlane32_swap((int)wb[1], (int)wb[3], false, false);
        b3.u[1] = (unsigned)r5[0]; b3.u[3] = (unsigned)r5[1];
        auto r6 = __builtin_amdgcn_permlane32_swap((int)wb[4], (int)wb[6], false, false);
        b4.u[0] = (unsigned)r6[0]; b4.u[2] = (unsigned)r6[1];
        auto r7 = __builtin_amdgcn_permlane32_swap((int)wb[5], (int)wb[7], false, false);
        b4.u[1] = (unsigned)r7[0]; b4.u[3] = (unsigned)r7[1];
    }
    acc = __builtin_amdgcn_mfma_f32_32x32x16_bf16(vf1, b1.v, acc, 0, 0, 0);
    acc = __builtin_amdgcn_mfma_f32_32x32x16_bf16(vf2, b2.v, acc, 0, 0, 0);
    acc = __builtin_amdgcn_mfma_f32_32x32x16_bf16(vf3, b3.v, acc, 0, 0, 0);
    acc = __builtin_amdgcn_mfma_f32_32x32x16_bf16(vf4, b4.v, acc, 0, 0, 0);
}

// ================= K3: MFMA attention — 2 Q-tiles per wave, shared K/V (R14-exact) =================
__global__ __launch_bounds__(128, 2) void k_attn(const bf16* __restrict__ qg, const bf16* __restrict__ kg,
                                                 const bf16* __restrict__ vg, bf16* __restrict__ pacc,
                                                 float2* __restrict__ psm) {
    int bh = blockIdx.x;            // (branch*2+b)*8+h
    int qblk = blockIdx.y;          // 0..15 (tile B = qblk+16)
    int split = blockIdx.z;         // 0..1
    size_t base = (size_t)bh * (2048 * 16);
    size_t vtbase = (size_t)bh * 32768;   // tiled V^T base (32 tiles x 1024)
    int tid = threadIdx.x, wave = tid >> 6, lane = tid & 63;
    int hi = lane >> 5, l31 = lane & 31;
    int qrowA = qblk * 64 + wave * 32 + l31;
    int qrowB = (qblk + 16) * 64 + wave * 32 + l31;
    const short* qs = (const short*)qg;
    const short* ks = (const short*)kg;
    const short* vts = (const short*)vg;
    short8 qfA = *(const short8*)&qs[base + (size_t)qrowA * 16 + hi * 8];
    short8 qfB = *(const short8*)&qs[base + (size_t)qrowB * 16 + hi * 8];

    short8 one8;
#pragma unroll
    for (int j = 0; j < 8; ++j) one8[j] = (short)0x3F80;   // bf16 1.0

    f32x16 accA, accB, negmA, negmB;
#pragma unroll
    for (int r = 0; r < 16; ++r) { accA[r] = 0.f; accB[r] = 0.f; negmA[r] = -16.f; negmB[r] = -16.f; }
    float mA = 16.f, mB = 16.f;

    int kbeg = split * 1024, kend = kbeg + 1024;

    for (int c0 = kbeg; c0 < kend; c0 += 64) {
        if (__any(accA[8] > 2.68435456e8f)) {   // 2^28
            int e = (__float_as_int(accA[8]) >> 23) - 127;
            int shift = e > 16 ? e - 16 : 0;
            float fac = __int_as_float((127 - shift) << 23);   // 2^-shift
            mA += (float)shift;
#pragma unroll
            for (int r = 0; r < 16; ++r) negmA[r] = -mA;
#pragma unroll
            for (int r = 0; r < 16; ++r) accA[r] *= fac;
        }
        if (__any(accB[8] > 2.68435456e8f)) {
            int e = (__float_as_int(accB[8]) >> 23) - 127;
            int shift = e > 16 ? e - 16 : 0;
            float fac = __int_as_float((127 - shift) << 23);
            mB += (float)shift;
#pragma unroll
            for (int r = 0; r < 16; ++r) negmB[r] = -mB;
#pragma unroll
            for (int r = 0; r < 16; ++r) accB[r] *= fac;
        }
        short8 kf0 = *(const short8*)&ks[base + (size_t)(c0 + l31) * 16 + hi * 8];
        short8 kf1 = *(const short8*)&ks[base + (size_t)(c0 + 32 + l31) * 16 + hi * 8];
        short8 vf1 = one8, vf2 = one8, vf3 = one8, vf4 = one8;
        if (l31 < 16) {
            const short* vt = &vts[vtbase + (size_t)(c0 >> 6) * 1024 + l31 * 64 + hi * 8];
            vf1 = *(const short8*)&vt[0];
            vf2 = *(const short8*)&vt[16];
            vf3 = *(const short8*)&vt[32];
            vf4 = *(const short8*)&vt[48];
        }
        attn_stream(kf0, kf1, vf1, vf2, vf3, vf4, qfA, negmA, accA);
        attn_stream(kf0, kf1, vf1, vf2, vf3, vf4, qfB, negmB, accB);
    }
    short* pp = (short*)pacc;
    {
        size_t pidx = ((size_t)(split * 48 + bh) * 2048 + qrowA) * 16;
        unsigned u0 = (unsigned)f2bu(accA[0]) | ((unsigned)f2bu(accA[1]) << 16);
        unsigned u1 = (unsigned)f2bu(accA[2]) | ((unsigned)f2bu(accA[3]) << 16);
        unsigned u2 = (unsigned)f2bu(accA[4]) | ((unsigned)f2bu(accA[5]) << 16);
        unsigned u3 = (unsigned)f2bu(accA[6]) | ((unsigned)f2bu(accA[7]) << 16);
        int2v w01; w01.x = (int)u0; w01.y = (int)u1;
        int2v w23; w23.x = (int)u2; w23.y = (int)u3;
        *(int2v*)&pp[pidx + 4 * hi] = w01;
        *(int2v*)&pp[pidx + 8 + 4 * hi] = w23;
        if (hi == 0) {
            float2 sm; sm.x = accA[8]; sm.y = mA;
            psm[(size_t)(split * 48 + bh) * 2048 + qrowA] = sm;
        }
    }
    {
        size_t pidx = ((size_t)(split * 48 + bh) * 2048 + qrowB) * 16;
        unsigned u0 = (unsigned)f2bu(accB[0]) | ((unsigned)f2bu(accB[1]) << 16);
        unsigned u1 = (unsigned)f2bu(accB[2]) | ((unsigned)f2bu(accB[3]) << 16);
        unsigned u2 = (unsigned)f2bu(accB[4]) | ((unsigned)f2bu(accB[5]) << 16);
        unsigned u3 = (unsigned)f2bu(accB[6]) | ((unsigned)f2bu(accB[7]) << 16);
        int2v w01; w01.x = (int)u0; w01.y = (int)u1;
        int2v w23; w23.x = (int)u2; w23.y = (int)u3;
        *(int2v*)&pp[pidx + 4 * hi] = w01;
        *(int2v*)&pp[pidx + 8 + 4 * hi] = w23;
        if (hi == 0) {
            float2 sm; sm.x = accB[8]; sm.y = mB;
            psm[(size_t)(split * 48 + bh) * 2048 + qrowB] = sm;
        }
    }
}

// ================= K4: proj GEMM with FUSED split-K merge in A-staging =================
__global__ __launch_bounds__(256) void k_proj_m(const bf16* __restrict__ pacc, const float2* __restrict__ psm,
                                                const bf16* __restrict__ wt, const float* __restrict__ pb,
                                                const float* __restrict__ x1, const float* __restrict__ x2,
                                                const float* __restrict__ x3, float* __restrict__ xc) {
    __shared__ short als[64 * 64];
    __shared__ short wls[64 * 64];
    int branch = blockIdx.z;
    const short* W = (const short*)wt + (size_t)branch * 128 * 128;
    const short* pp = (const short*)pacc;
    int rowbase = blockIdx.x * 64, colbase = blockIdx.y * 64;
    int tid = threadIdx.x;
    int wid = tid >> 6, lane = tid & 63;
    int hi = lane >> 5, l31 = lane & 31;
    int wm = wid >> 1, wn = wid & 1;
    int sr = tid >> 3, skb = tid & 7;
    f32x16 acc;
#pragma unroll
    for (int i = 0; i < 16; ++i) acc[i] = 0.f;
    for (int k0 = 0; k0 < 128; k0 += 64) {
        __syncthreads();
#pragma unroll
        for (int pass = 0; pass < 2; ++pass) {
            int r = sr + pass * 32;
            int row = rowbase + r;                  // token row within branch
            int bb = row >> 11, n = row & 2047;
            int h = (k0 >> 4) + (skb >> 1);         // head for these 8 cols
            int dlo = (skb & 1) * 8;                // d offset (0 or 8)
            size_t bh = (size_t)(branch * 2 + bb) * 8 + h;
            size_t ridx = bh * 2048 + n;
            float2 sm0 = psm[ridx];
            float2 sm1 = psm[(size_t)48 * 2048 + ridx];
            float mp = fmaxf(sm0.y, sm1.y);
            float w0 = __builtin_amdgcn_exp2f(sm0.y - mp);
            float w1 = __builtin_amdgcn_exp2f(sm1.y - mp);
            float inv = 1.f / (sm0.x * w0 + sm1.x * w1);
            w0 *= inv; w1 *= inv;
            short8 a0 = *(const short8*)&pp[ridx * 16 + dlo];
            short8 a1 = *(const short8*)&pp[((size_t)48 * 2048 + ridx) * 16 + dlo];
            short8 av;
#pragma unroll
            for (int j = 0; j < 8; ++j)
                av[j] = (short)f2bu(bs2f(a0[j]) * w0 + bs2f(a1[j]) * w1);
            *(short8*)&als[r * 64 + ((skb ^ (r & 7)) * 8)] = av;
            short8 wv = *(const short8*)&W[(size_t)(colbase + r) * 128 + k0 + skb * 8];
            *(short8*)&wls[r * 64 + ((skb ^ (r & 7)) * 8)] = wv;
        }
        __syncthreads();
#pragma unroll
        for (int ks = 0; ks < 4; ++ks) {
            int ra = wm * 32 + l31;
            int rb = wn * 32 + l31;
            int kb = ks * 2 + hi;
            short8 af = *(const short8*)&als[ra * 64 + ((kb ^ (ra & 7)) * 8)];
            short8 bf = *(const short8*)&wls[rb * 64 + ((kb ^ (rb & 7)) * 8)];
            acc = __builtin_amdgcn_mfma_f32_32x32x16_bf16(af, bf, acc, 0, 0, 0);
        }
    }
    int c = colbase + wn * 32 + l31;        // 0..127
    float bias = pb[branch * 128 + c];
    const float* xp = (branch == 0) ? x1 : (branch == 1 ? x2 : x3);
#pragma unroll
    for (int i = 0; i < 16; ++i) {
        int mrow = (i & 3) + 8 * (i >> 2) + 4 * hi;
        int row = rowbase + wm * 32 + mrow;
        xc[(size_t)row * 384 + branch * 128 + c] = acc[i] + bias + xp[(size_t)row * 128 + c];
    }
}

// ================= K5: LN2 over 384 features =================
__global__ __launch_bounds__(256) void k_ln2(const float* __restrict__ xc, const float* __restrict__ g,
                                             const float* __restrict__ b, bf16* __restrict__ xcn) {
    int tid = threadIdx.x, wave = tid >> 6, lane = tid & 63;
    int row = blockIdx.x * 4 + wave;  // 0..4095
    const float* rp = xc + (size_t)row * 384;
    float v[6];
    float s = 0.f, sq = 0.f;
#pragma unroll
    for (int i = 0; i < 6; ++i) {
        v[i] = rp[lane + i * 64];
        s += v[i]; sq += v[i] * v[i];
    }
#pragma unroll
    for (int off = 32; off >= 1; off >>= 1) { s += __shfl_xor(s, off); sq += __shfl_xor(sq, off); }
    float mean = s * (1.f / 384.f);
    float var = sq * (1.f / 384.f) - mean * mean;
    float rstd = rsqrtf(var + 1e-5f);
    bf16* op = xcn + (size_t)row * 384;
#pragma unroll
    for (int i = 0; i < 6; ++i) {
        int c = lane + i * 64;
        op[c] = f2b((v[i] - mean) * rstd * g[c] + b[c]);
    }
}

// ================= K6: FC1 GEMM (64x128 tile) + bias + exact GELU -> h bf16 =================
__global__ __launch_bounds__(256) void k_fc1_m(const bf16* __restrict__ xcn, const bf16* __restrict__ wt,
                                               const float* __restrict__ bias, bf16* __restrict__ h) {
    __shared__ short als[64 * 64];     // 8 KB
    __shared__ short wls[128 * 64];    // 16 KB
    const short* A = (const short*)xcn;
    const short* W = (const short*)wt;
    int rowbase = blockIdx.x * 64, colbase = blockIdx.y * 128;
    f32x16 acc0, acc1;
    gemm_tile2(A, W, 384, rowbase, colbase, als, wls, acc0, acc1);
    int tid = threadIdx.x, wid = tid >> 6, lane = tid & 63;
    int hi = lane >> 5, l31 = lane & 31;
    int wm = wid >> 1, wn = wid & 1;
    int c0 = colbase + wn * 64 + l31;       // 0..767
    int c1 = c0 + 32;
    float bs0 = bias[c0];
    float bs1 = bias[c1];
#pragma unroll
    for (int i = 0; i < 16; ++i) {
        int mrow = (i & 3) + 8 * (i >> 2) + 4 * hi;
        int row = rowbase + wm * 32 + mrow;
        float v0 = acc0[i] + bs0;
        float v1 = acc1[i] + bs1;
        float g0 = 0.5f * v0 * (1.f + erff(v0 * 0.70710678118f));
        float g1 = 0.5f * v1 * (1.f + erff(v1 * 0.70710678118f));
        h[(size_t)row * 768 + c0] = f2b(g0);
        h[(size_t)row * 768 + c1] = f2b(g1);
    }
}

// ================= K7: FC2 GEMM (MFMA) + bias + residual -> split fp32 outputs =================
__global__ __launch_bounds__(256) void k_fc2_m(const bf16* __restrict__ h, const bf16* __restrict__ wt,
                                               const float* __restrict__ bias, const float* __restrict__ xc,
                                               float* __restrict__ outp) {
    __shared__ short als[64 * 64];
    __shared__ short wls[64 * 64];
    const short* A = (const short*)h;
    const short* W = (const short*)wt;
    int rowbase = blockIdx.x * 64, colbase = blockIdx.y * 64;
    f32x16 acc = gemm_tile(A, W, 768, rowbase, colbase, als, wls);
    int tid = threadIdx.x, wid = tid >> 6, lane = tid & 63;
    int hi = lane >> 5, l31 = lane & 31;
    int wm = wid >> 1, wn = wid & 1;
    int c = colbase + wn * 32 + l31;        // 0..383
    float bs = bias[c];
    int which = c >> 7, cc = c & 127;
#pragma unroll
    for (int i = 0; i < 16; ++i) {
        int mrow = (i & 3) + 8 * (i >> 2) + 4 * hi;
        int row = rowbase + wm * 32 + mrow;
        outp[(size_t)which * 524288 + (size_t)row * 128 + cc] = acc[i] + bs + xc[(size_t)row * 384 + c];
    }
}

// ================= launch =================
extern "C" void kernel_launch(void* const* d_in, const int* in_sizes, int n_in,
                              void* d_out, int out_size, void* d_ws, size_t ws_size,
                              hipStream_t stream) {
    const float* x1     = (const float*)d_in[0];
    const float* x2     = (const float*)d_in[1];
    const float* x3     = (const float*)d_in[2];
    const float* ln1_g  = (const float*)d_in[3];
    const float* ln1_b  = (const float*)d_in[4];
    const float* qkv_w  = (const float*)d_in[5];
    const float* proj_w = (const float*)d_in[6];
    const float* proj_b = (const float*)d_in[7];
    const float* ln2_g  = (const float*)d_in[8];
    const float* ln2_b  = (const float*)d_in[9];
    const float* fc1_w  = (const float*)d_in[10];
    const float* fc1_b  = (const float*)d_in[11];
    const float* fc2_w  = (const float*)d_in[12];
    const float* fc2_b  = (const float*)d_in[13];

    char* ws = (char*)d_ws;
    const size_t SB = 3145728;  // bf16 buffer of 1.5M elems
    bf16* xn  = (bf16*)(ws + 0 * SB);
    bf16* qb  = (bf16*)(ws + 1 * SB);
    bf16* kb  = (bf16*)(ws + 2 * SB);
    bf16* vb  = (bf16*)(ws + 3 * SB);   // tiled V^T
    float* xc = (float*)(ws + 5 * SB);            // 4096*384*4 = 6291456 B
    bf16* xcn = (bf16*)(ws + 5 * SB + 6291456);   // 3145728 B
    bf16* hb  = (bf16*)(ws + 6 * SB + 6291456);   // 4096*768*2 = 6291456 B
    char* wbase = ws + 31457280;
    bf16* wtq = (bf16*)(wbase);                   // 3*384*128*2 = 294912
    bf16* wtp = (bf16*)(wbase + 294912);          // 3*128*128*2 = 98304
    bf16* wt1 = (bf16*)(wbase + 393216);          // 768*384*2   = 589824
    bf16* wt2 = (bf16*)(wbase + 983040);          // 384*768*2   = 589824
    // total = 33030144 B (~31.5 MB)
    // Split-K attention partials OVERLAY xcn+hb (both written only after proj reads them):
    bf16*  pacc = (bf16*)(ws + 22020096);         // 2*48*2048*16*2 = 6291456 B
    float2* psm = (float2*)(ws + 28311552);       // 2*48*2048*8    = 1572864 B

    k_pre<<<6144, 256, 0, stream>>>(x1, x2, x3, ln1_g, ln1_b, xn,
                                    qkv_w, proj_w, fc1_w, fc2_w, wtq, wtp, wt1, wt2);
    k_qkv_m<<<dim3(64, 3, 3), 256, 0, stream>>>(xn, wtq, qb, kb, vb);
    k_attn<<<dim3(48, 16, 2), 128, 0, stream>>>(qb, kb, vb, pacc, psm);
    k_proj_m<<<dim3(64, 2, 3), 256, 0, stream>>>(pacc, psm, wtp, proj_b, x1, x2, x3, xc);
    k_ln2<<<1024, 256, 0, stream>>>(xc, ln2_g, ln2_b, xcn);
    k_fc1_m<<<dim3(64, 6, 1), 256, 0, stream>>>(xcn, wt1, fc1_b, hb);
    k_fc2_m<<<dim3(64, 6, 1), 256, 0, stream>>>(hb, wt2, fc2_b, xc, (float*)d_out);
}

// Round 18
// 84.468 us; speedup vs baseline: 1.4154x; 1.0026x over previous
//
#include <hip/hip_runtime.h>
#include <hip/hip_bf16.h>

typedef __hip_bfloat16 bf16;

// ---------- constants ----------
// B=2, N=2048, C=128, H=8, hd=16, branches=3, hid=768
// rows per branch = B*N = 4096; 3C = 384
// I/O fp32; intermediates bf16 except xc (fp32 residual). Weights pre-transposed
// to bf16 Wt[N][K] (fused into k_pre). Q pre-scaled by 0.25*log2e (exp2-domain).
// V stored as tiled V^T: [bh][kb=key/64][d=16][key%64]. Attention: barrier-free,
// LDS-free, split-K (2x1024), two Q-tiles per wave with SHARED negm/m (merged
// guarded rescale, exact pow2), launch_bounds(128,3) for 3 waves/SIMD.
// qkv/fc1 GEMMs 64x128 tiles; proj/fc2 64x64. Split-K merge fused into k_proj_m.

static __device__ __forceinline__ float b2f(bf16 h) { return __bfloat162float(h); }
static __device__ __forceinline__ bf16 f2b(float f) { return __float2bfloat16(f); }
static __device__ __forceinline__ unsigned short f2bu(float f) {
    bf16 h = f2b(f);
    return *reinterpret_cast<unsigned short*>(&h);
}
static __device__ __forceinline__ float bs2f(short s) {
    return __uint_as_float(((unsigned)(unsigned short)s) << 16);
}

typedef __attribute__((ext_vector_type(8))) short short8;
typedef __attribute__((ext_vector_type(4))) short short4v;
typedef __attribute__((ext_vector_type(16))) float f32x16;
typedef __attribute__((ext_vector_type(2))) int int2v;

#define QSCALE 0.36067376022224085f  // 0.25 * log2(e)

// ================= K0: fused weight transpose+convert AND LN1 =================
__global__ __launch_bounds__(256) void k_pre(const float* __restrict__ x1, const float* __restrict__ x2,
                                             const float* __restrict__ x3, const float* __restrict__ g,
                                             const float* __restrict__ b, bf16* __restrict__ xn,
                                             const float* __restrict__ qkv_w, const float* __restrict__ proj_w,
                                             const float* __restrict__ fc1_w, const float* __restrict__ fc2_w,
                                             bf16* __restrict__ wtq, bf16* __restrict__ wtp,
                                             bf16* __restrict__ wt1, bf16* __restrict__ wt2) {
    if (blockIdx.x >= 3072) {
        int idx = (blockIdx.x - 3072) * 256 + threadIdx.x;   // < 786432
        if (idx < 147456) {
            int bq = idx / 49152, i2 = idx % 49152;
            int n = i2 >> 7, k = i2 & 127;
            wtq[idx] = f2b(qkv_w[bq * 49152 + k * 384 + n]);
        } else if (idx < 196608) {
            int j = idx - 147456;
            int bq = j / 16384, i2 = j % 16384;
            int n = i2 >> 7, k = i2 & 127;
            wtp[j] = f2b(proj_w[bq * 16384 + k * 128 + n]);
        } else if (idx < 491520) {
            int j = idx - 196608;
            int n = j / 384, k = j - n * 384;
            wt1[j] = f2b(fc1_w[k * 768 + n]);
        } else {
            int j = idx - 491520;
            int n = j / 768, k = j - n * 768;
            wt2[j] = f2b(fc2_w[k * 384 + n]);
        }
        return;
    }
    int tid = threadIdx.x;
    int wave = tid >> 6, lane = tid & 63;
    int grow = blockIdx.x * 4 + wave;      // 0..12287
    int branch = grow >> 12;
    const float* xp = (branch == 0) ? x1 : (branch == 1 ? x2 : x3);
    const float* row = xp + (size_t)(grow & 4095) * 128;
    float2 a = *reinterpret_cast<const float2*>(&row[2 * lane]);
    float s = a.x + a.y, sq = a.x * a.x + a.y * a.y;
#pragma unroll
    for (int off = 32; off >= 1; off >>= 1) { s += __shfl_xor(s, off); sq += __shfl_xor(sq, off); }
    float mean = s * (1.f / 128.f);
    float var = sq * (1.f / 128.f) - mean * mean;
    float rstd = rsqrtf(var + 1e-5f);
    float2 gv = *reinterpret_cast<const float2*>(&g[branch * 128 + 2 * lane]);
    float2 bv = *reinterpret_cast<const float2*>(&b[branch * 128 + 2 * lane]);
    bf16* orow = xn + (size_t)grow * 128;
    orow[2 * lane] = f2b((a.x - mean) * rstd * gv.x + bv.x);
    orow[2 * lane + 1] = f2b((a.y - mean) * rstd * gv.y + bv.y);
}

// ================= shared MFMA GEMM tile: C64x64 = A[M,K] . Wt[N,K]^T =================
__device__ __forceinline__ f32x16 gemm_tile(const short* __restrict__ A, const short* __restrict__ W,
                                            int K, int rowbase, int colbase,
                                            short* als, short* wls) {
    int tid = threadIdx.x;
    int wid = tid >> 6, lane = tid & 63;
    int hi = lane >> 5, l31 = lane & 31;
    int wm = wid >> 1, wn = wid & 1;
    int sr = tid >> 3, skb = tid & 7;   // staging: row (0..31), k-block (0..7)
    f32x16 acc;
#pragma unroll
    for (int i = 0; i < 16; ++i) acc[i] = 0.f;
    for (int k0 = 0; k0 < K; k0 += 64) {
        __syncthreads();
#pragma unroll
        for (int pass = 0; pass < 2; ++pass) {
            int r = sr + pass * 32;
            short8 av = *(const short8*)&A[(size_t)(rowbase + r) * K + k0 + skb * 8];
            *(short8*)&als[r * 64 + ((skb ^ (r & 7)) * 8)] = av;
            short8 wv = *(const short8*)&W[(size_t)(colbase + r) * K + k0 + skb * 8];
            *(short8*)&wls[r * 64 + ((skb ^ (r & 7)) * 8)] = wv;
        }
        __syncthreads();
#pragma unroll
        for (int ks = 0; ks < 4; ++ks) {
            int ra = wm * 32 + l31;
            int rb = wn * 32 + l31;
            int kb = ks * 2 + hi;
            short8 af = *(const short8*)&als[ra * 64 + ((kb ^ (ra & 7)) * 8)];
            short8 bf = *(const short8*)&wls[rb * 64 + ((kb ^ (rb & 7)) * 8)];
            acc = __builtin_amdgcn_mfma_f32_32x32x16_bf16(af, bf, acc, 0, 0, 0);
        }
    }
    return acc;
}

// ================= wide MFMA GEMM tile: C64x128 = A[M,K] . Wt[N,K]^T (2 accs) =================
__device__ __forceinline__ void gemm_tile2(const short* __restrict__ A, const short* __restrict__ W,
                                           int K, int rowbase, int colbase,
                                           short* als, short* wls, f32x16& acc0, f32x16& acc1) {
    int tid = threadIdx.x;
    int wid = tid >> 6, lane = tid & 63;
    int hi = lane >> 5, l31 = lane & 31;
    int wm = wid >> 1, wn = wid & 1;
    int sr = tid >> 3, skb = tid & 7;
#pragma unroll
    for (int i = 0; i < 16; ++i) { acc0[i] = 0.f; acc1[i] = 0.f; }
    for (int k0 = 0; k0 < K; k0 += 64) {
        __syncthreads();
#pragma unroll
        for (int pass = 0; pass < 2; ++pass) {
            int r = sr + pass * 32;
            short8 av = *(const short8*)&A[(size_t)(rowbase + r) * K + k0 + skb * 8];
            *(short8*)&als[r * 64 + ((skb ^ (r & 7)) * 8)] = av;
        }
#pragma unroll
        for (int pass = 0; pass < 4; ++pass) {
            int r = sr + pass * 32;   // 0..127 (W rows = output cols)
            short8 wv = *(const short8*)&W[(size_t)(colbase + r) * K + k0 + skb * 8];
            *(short8*)&wls[r * 64 + ((skb ^ (r & 7)) * 8)] = wv;
        }
        __syncthreads();
#pragma unroll
        for (int ks = 0; ks < 4; ++ks) {
            int ra = wm * 32 + l31;
            int rb0 = wn * 64 + l31;
            int rb1 = wn * 64 + 32 + l31;
            int kb = ks * 2 + hi;
            short8 af = *(const short8*)&als[ra * 64 + ((kb ^ (ra & 7)) * 8)];
            short8 bf0 = *(const short8*)&wls[rb0 * 64 + ((kb ^ (rb0 & 7)) * 8)];
            short8 bf1 = *(const short8*)&wls[rb1 * 64 + ((kb ^ (rb1 & 7)) * 8)];
            acc0 = __builtin_amdgcn_mfma_f32_32x32x16_bf16(af, bf0, acc0, 0, 0, 0);
            acc1 = __builtin_amdgcn_mfma_f32_32x32x16_bf16(af, bf1, acc1, 0, 0, 0);
        }
    }
}

// ================= K2: QKV GEMM (64x128 tile); Q pre-scaled; V tiled-transposed =================
__global__ __launch_bounds__(256) void k_qkv_m(const bf16* __restrict__ xn, const bf16* __restrict__ wt,
                                               bf16* __restrict__ q, bf16* __restrict__ k, bf16* __restrict__ v) {
    __shared__ short als[64 * 64];     // 8 KB
    __shared__ short wls[128 * 64];    // 16 KB
    int branch = blockIdx.z;
    const short* A = (const short*)xn + (size_t)branch * 4096 * 128;
    const short* W = (const short*)wt + (size_t)branch * 384 * 128;
    int rowbase = blockIdx.x * 64, colbase = blockIdx.y * 128;
    f32x16 acc0, acc1;
    gemm_tile2(A, W, 128, rowbase, colbase, als, wls, acc0, acc1);
    int tid = threadIdx.x, wid = tid >> 6, lane = tid & 63;
    int hi = lane >> 5, l31 = lane & 31;
    int wm = wid >> 1, wn = wid & 1;
    int which = blockIdx.y;                 // 0=q, 1=k, 2=v (block-uniform)
    int c0 = wn * 64 + l31;                 // 0..127 within slab
    int c1 = c0 + 32;
    if (which < 2) {
        bf16* dst = (which == 0) ? q : k;
        float scl = (which == 0) ? QSCALE : 1.0f;
        int h0 = c0 >> 4, d0 = c0 & 15;
        int h1 = c1 >> 4, d1 = c1 & 15;
#pragma unroll
        for (int i = 0; i < 16; ++i) {
            int mrow = (i & 3) + 8 * (i >> 2) + 4 * hi;
            int token = rowbase + wm * 32 + mrow;
            int bb = token >> 11, n = token & 2047;
            size_t rowb = (((size_t)branch * 2 + bb) * 8);
            dst[((rowb + h0) * 2048 + n) * 16 + d0] = f2b(acc0[i] * scl);
            dst[((rowb + h1) * 2048 + n) * 16 + d1] = f2b(acc1[i] * scl);
        }
    } else {
        int h0 = c0 >> 4, d0 = c0 & 15;
        int h1 = c1 >> 4, d1 = c1 & 15;
#pragma unroll
        for (int i = 0; i < 16; ++i) {
            int mrow = (i & 3) + 8 * (i >> 2) + 4 * hi;
            int token = rowbase + wm * 32 + mrow;
            int bb = token >> 11, n = token & 2047;
            size_t bhb = ((size_t)(branch * 2 + bb) * 8);
            v[(((bhb + h0) * 32 + (n >> 6)) * 16 + d0) * 64 + (n & 63)] = f2b(acc0[i]);
            v[(((bhb + h1) * 32 + (n >> 6)) * 16 + d1) * 64 + (n & 63)] = f2b(acc1[i]);
        }
    }
}

// ---- one attention stream: QK (C=-m) -> exp2 -> cvt_pk -> permlane -> 4 PV into acc ----
static __device__ __forceinline__ void attn_stream(short8 kf0, short8 kf1,
                                                   short8 vf1, short8 vf2, short8 vf3, short8 vf4,
                                                   short8 qf, const f32x16& negm, f32x16& acc) {
    f32x16 pa = __builtin_amdgcn_mfma_f32_32x32x16_bf16(kf0, qf, negm, 0, 0, 0);
    f32x16 pb = __builtin_amdgcn_mfma_f32_32x32x16_bf16(kf1, qf, negm, 0, 0, 0);
#pragma unroll
    for (int r = 0; r < 16; ++r) pa[r] = __builtin_amdgcn_exp2f(pa[r]);
#pragma unroll
    for (int r = 0; r < 16; ++r) pb[r] = __builtin_amdgcn_exp2f(pb[r]);
    unsigned wa[8], wb[8];
#pragma unroll
    for (int e = 0; e < 8; ++e) {
        unsigned t;
        asm("v_cvt_pk_bf16_f32 %0, %1, %2" : "=v"(t) : "v"(pa[2 * e]), "v"(pa[2 * e + 1]));
        wa[e] = t;
        asm("v_cvt_pk_bf16_f32 %0, %1, %2" : "=v"(t) : "v"(pb[2 * e]), "v"(pb[2 * e + 1]));
        wb[e] = t;
    }
    union { unsigned u[4]; short8 v; } b1, b2, b3, b4;
    {
        auto r0 = __builtin_amdgcn_permlane32_swap((int)wa[0], (int)wa[2], false, false);
        b1.u[0] = (unsigned)r0[0]; b1.u[2] = (unsigned)r0[1];
        auto r1 = __builtin_amdgcn_permlane32_swap((int)wa[1], (int)wa[3], false, false);
        b1.u[1] = (unsigned)r1[0]; b1.u[3] = (unsigned)r1[1];
        auto r2 = __builtin_amdgcn_permlane32_swap((int)wa[4], (int)wa[6], false, false);
        b2.u[0] = (unsigned)r2[0]; b2.u[2] = (unsigned)r2[1];
        auto r3 = __builtin_amdgcn_permlane32_swap((int)wa[5], (int)wa[7], false, false);
        b2.u[1] = (unsigned)r3[0]; b2.u[3] = (unsigned)r3[1];
        auto r4 = __builtin_amdgcn_permlane32_swap((int)wb[0], (int)wb[2], false, false);
        b3.u[0] = (unsigned)r4[0]; b3.u[2] = (unsigned)r4[1];
        auto r5 = __builtin_amdgcn_permlane32_swap((int)wb[1], (int)wb[3], false, false);
        b3.u[1] = (unsigned)r5[0]; b3.u[3] = (unsigned)r5[1];
        auto r6 = __builtin_amdgcn_permlane32_swap((int)wb[4], (int)wb[6], false, false);
        b4.u[0] = (unsigned)r6[0]; b4.u[2] = (unsigned)r6[1];
        auto r7 = __builtin_amdgcn_permlane32_swap((int)wb[5], (int)wb[7], false, false);
        b4.u[1] = (unsigned)r7[0]; b4.u[3] = (unsigned)r7[1];
    }
    acc = __builtin_amdgcn_mfma_f32_32x32x16_bf16(vf1, b1.v, acc, 0, 0, 0);
    acc = __builtin_amdgcn_mfma_f32_32x32x16_bf16(vf2, b2.v, acc, 0, 0, 0);
    acc = __builtin_amdgcn_mfma_f32_32x32x16_bf16(vf3, b3.v, acc, 0, 0, 0);
    acc = __builtin_amdgcn_mfma_f32_32x32x16_bf16(vf4, b4.v, acc, 0, 0, 0);
}

// ================= K3: MFMA attention — 2 Q-tiles per wave, SHARED negm/m =================
// grid (48 bh, 16, 2 split), 128 threads = 2 waves; launch_bounds(128,3) for occupancy.
// Merged guarded rescale: if either stream's acc[8] exceeds 2^28, BOTH accs are scaled
// by the same 2^-shift (exact pow2; shift from the per-lane max). Loop-carried guard
// reads on both accs preserved (R11/R12 lesson).
__global__ __launch_bounds__(128, 3) void k_attn(const bf16* __restrict__ qg, const bf16* __restrict__ kg,
                                                 const bf16* __restrict__ vg, bf16* __restrict__ pacc,
                                                 float2* __restrict__ psm) {
    int bh = blockIdx.x;            // (branch*2+b)*8+h
    int qblk = blockIdx.y;          // 0..15 (tile B = qblk+16)
    int split = blockIdx.z;         // 0..1
    size_t base = (size_t)bh * (2048 * 16);
    size_t vtbase = (size_t)bh * 32768;   // tiled V^T base (32 tiles x 1024)
    int tid = threadIdx.x, wave = tid >> 6, lane = tid & 63;
    int hi = lane >> 5, l31 = lane & 31;
    int qrowA = qblk * 64 + wave * 32 + l31;
    int qrowB = (qblk + 16) * 64 + wave * 32 + l31;
    const short* qs = (const short*)qg;
    const short* ks = (const short*)kg;
    const short* vts = (const short*)vg;
    short8 qfA = *(const short8*)&qs[base + (size_t)qrowA * 16 + hi * 8];
    short8 qfB = *(const short8*)&qs[base + (size_t)qrowB * 16 + hi * 8];

    short8 one8;
#pragma unroll
    for (int j = 0; j < 8; ++j) one8[j] = (short)0x3F80;   // bf16 1.0

    f32x16 accA, accB, negm;
#pragma unroll
    for (int r = 0; r < 16; ++r) { accA[r] = 0.f; accB[r] = 0.f; negm[r] = -16.f; }
    float m = 16.f;

    int kbeg = split * 1024, kend = kbeg + 1024;

    for (int c0 = kbeg; c0 < kend; c0 += 64) {
        // merged guarded rescale (loop-carried reads of BOTH acc[8]); exact pow2 scale
        float mx = fmaxf(accA[8], accB[8]);
        if (__any(mx > 2.68435456e8f)) {   // 2^28
            int e = (__float_as_int(mx) >> 23) - 127;
            int shift = e > 16 ? e - 16 : 0;
            float fac = __int_as_float((127 - shift) << 23);   // 2^-shift
            m += (float)shift;
#pragma unroll
            for (int r = 0; r < 16; ++r) negm[r] = -m;
#pragma unroll
            for (int r = 0; r < 16; ++r) { accA[r] *= fac; accB[r] *= fac; }
        }
        short8 kf0 = *(const short8*)&ks[base + (size_t)(c0 + l31) * 16 + hi * 8];
        short8 kf1 = *(const short8*)&ks[base + (size_t)(c0 + 32 + l31) * 16 + hi * 8];
        short8 vf1 = one8, vf2 = one8, vf3 = one8, vf4 = one8;
        if (l31 < 16) {
            const short* vt = &vts[vtbase + (size_t)(c0 >> 6) * 1024 + l31 * 64 + hi * 8];
            vf1 = *(const short8*)&vt[0];
            vf2 = *(const short8*)&vt[16];
            vf3 = *(const short8*)&vt[32];
            vf4 = *(const short8*)&vt[48];
        }
        attn_stream(kf0, kf1, vf1, vf2, vf3, vf4, qfA, negm, accA);
        attn_stream(kf0, kf1, vf1, vf2, vf3, vf4, qfB, negm, accB);
    }
    short* pp = (short*)pacc;
    {
        size_t pidx = ((size_t)(split * 48 + bh) * 2048 + qrowA) * 16;
        unsigned u0 = (unsigned)f2bu(accA[0]) | ((unsigned)f2bu(accA[1]) << 16);
        unsigned u1 = (unsigned)f2bu(accA[2]) | ((unsigned)f2bu(accA[3]) << 16);
        unsigned u2 = (unsigned)f2bu(accA[4]) | ((unsigned)f2bu(accA[5]) << 16);
        unsigned u3 = (unsigned)f2bu(accA[6]) | ((unsigned)f2bu(accA[7]) << 16);
        int2v w01; w01.x = (int)u0; w01.y = (int)u1;
        int2v w23; w23.x = (int)u2; w23.y = (int)u3;
        *(int2v*)&pp[pidx + 4 * hi] = w01;
        *(int2v*)&pp[pidx + 8 + 4 * hi] = w23;
        if (hi == 0) {
            float2 sm; sm.x = accA[8]; sm.y = m;
            psm[(size_t)(split * 48 + bh) * 2048 + qrowA] = sm;
        }
    }
    {
        size_t pidx = ((size_t)(split * 48 + bh) * 2048 + qrowB) * 16;
        unsigned u0 = (unsigned)f2bu(accB[0]) | ((unsigned)f2bu(accB[1]) << 16);
        unsigned u1 = (unsigned)f2bu(accB[2]) | ((unsigned)f2bu(accB[3]) << 16);
        unsigned u2 = (unsigned)f2bu(accB[4]) | ((unsigned)f2bu(accB[5]) << 16);
        unsigned u3 = (unsigned)f2bu(accB[6]) | ((unsigned)f2bu(accB[7]) << 16);
        int2v w01; w01.x = (int)u0; w01.y = (int)u1;
        int2v w23; w23.x = (int)u2; w23.y = (int)u3;
        *(int2v*)&pp[pidx + 4 * hi] = w01;
        *(int2v*)&pp[pidx + 8 + 4 * hi] = w23;
        if (hi == 0) {
            float2 sm; sm.x = accB[8]; sm.y = m;
            psm[(size_t)(split * 48 + bh) * 2048 + qrowB] = sm;
        }
    }
}

// ================= K4: proj GEMM with FUSED split-K merge in A-staging =================
__global__ __launch_bounds__(256) void k_proj_m(const bf16* __restrict__ pacc, const float2* __restrict__ psm,
                                                const bf16* __restrict__ wt, const float* __restrict__ pb,
                                                const float* __restrict__ x1, const float* __restrict__ x2,
                                                const float* __restrict__ x3, float* __restrict__ xc) {
    __shared__ short als[64 * 64];
    __shared__ short wls[64 * 64];
    int branch = blockIdx.z;
    const short* W = (const short*)wt + (size_t)branch * 128 * 128;
    const short* pp = (const short*)pacc;
    int rowbase = blockIdx.x * 64, colbase = blockIdx.y * 64;
    int tid = threadIdx.x;
    int wid = tid >> 6, lane = tid & 63;
    int hi = lane >> 5, l31 = lane & 31;
    int wm = wid >> 1, wn = wid & 1;
    int sr = tid >> 3, skb = tid & 7;
    f32x16 acc;
#pragma unroll
    for (int i = 0; i < 16; ++i) acc[i] = 0.f;
    for (int k0 = 0; k0 < 128; k0 += 64) {
        __syncthreads();
#pragma unroll
        for (int pass = 0; pass < 2; ++pass) {
            int r = sr + pass * 32;
            int row = rowbase + r;                  // token row within branch
            int bb = row >> 11, n = row & 2047;
            int h = (k0 >> 4) + (skb >> 1);         // head for these 8 cols
            int dlo = (skb & 1) * 8;                // d offset (0 or 8)
            size_t bh = (size_t)(branch * 2 + bb) * 8 + h;
            size_t ridx = bh * 2048 + n;
            float2 sm0 = psm[ridx];
            float2 sm1 = psm[(size_t)48 * 2048 + ridx];
            float mp = fmaxf(sm0.y, sm1.y);
            float w0 = __builtin_amdgcn_exp2f(sm0.y - mp);
            float w1 = __builtin_amdgcn_exp2f(sm1.y - mp);
            float inv = 1.f / (sm0.x * w0 + sm1.x * w1);
            w0 *= inv; w1 *= inv;
            short8 a0 = *(const short8*)&pp[ridx * 16 + dlo];
            short8 a1 = *(const short8*)&pp[((size_t)48 * 2048 + ridx) * 16 + dlo];
            short8 av;
#pragma unroll
            for (int j = 0; j < 8; ++j)
                av[j] = (short)f2bu(bs2f(a0[j]) * w0 + bs2f(a1[j]) * w1);
            *(short8*)&als[r * 64 + ((skb ^ (r & 7)) * 8)] = av;
            short8 wv = *(const short8*)&W[(size_t)(colbase + r) * 128 + k0 + skb * 8];
            *(short8*)&wls[r * 64 + ((skb ^ (r & 7)) * 8)] = wv;
        }
        __syncthreads();
#pragma unroll
        for (int ks = 0; ks < 4; ++ks) {
            int ra = wm * 32 + l31;
            int rb = wn * 32 + l31;
            int kb = ks * 2 + hi;
            short8 af = *(const short8*)&als[ra * 64 + ((kb ^ (ra & 7)) * 8)];
            short8 bf = *(const short8*)&wls[rb * 64 + ((kb ^ (rb & 7)) * 8)];
            acc = __builtin_amdgcn_mfma_f32_32x32x16_bf16(af, bf, acc, 0, 0, 0);
        }
    }
    int c = colbase + wn * 32 + l31;        // 0..127
    float bias = pb[branch * 128 + c];
    const float* xp = (branch == 0) ? x1 : (branch == 1 ? x2 : x3);
#pragma unroll
    for (int i = 0; i < 16; ++i) {
        int mrow = (i & 3) + 8 * (i >> 2) + 4 * hi;
        int row = rowbase + wm * 32 + mrow;
        xc[(size_t)row * 384 + branch * 128 + c] = acc[i] + bias + xp[(size_t)row * 128 + c];
    }
}

// ================= K5: LN2 over 384 features =================
__global__ __launch_bounds__(256) void k_ln2(const float* __restrict__ xc, const float* __restrict__ g,
                                             const float* __restrict__ b, bf16* __restrict__ xcn) {
    int tid = threadIdx.x, wave = tid >> 6, lane = tid & 63;
    int row = blockIdx.x * 4 + wave;  // 0..4095
    const float* rp = xc + (size_t)row * 384;
    float v[6];
    float s = 0.f, sq = 0.f;
#pragma unroll
    for (int i = 0; i < 6; ++i) {
        v[i] = rp[lane + i * 64];
        s += v[i]; sq += v[i] * v[i];
    }
#pragma unroll
    for (int off = 32; off >= 1; off >>= 1) { s += __shfl_xor(s, off); sq += __shfl_xor(sq, off); }
    float mean = s * (1.f / 384.f);
    float var = sq * (1.f / 384.f) - mean * mean;
    float rstd = rsqrtf(var + 1e-5f);
    bf16* op = xcn + (size_t)row * 384;
#pragma unroll
    for (int i = 0; i < 6; ++i) {
        int c = lane + i * 64;
        op[c] = f2b((v[i] - mean) * rstd * g[c] + b[c]);
    }
}

// ================= K6: FC1 GEMM (64x128 tile) + bias + exact GELU -> h bf16 =================
__global__ __launch_bounds__(256) void k_fc1_m(const bf16* __restrict__ xcn, const bf16* __restrict__ wt,
                                               const float* __restrict__ bias, bf16* __restrict__ h) {
    __shared__ short als[64 * 64];     // 8 KB
    __shared__ short wls[128 * 64];    // 16 KB
    const short* A = (const short*)xcn;
    const short* W = (const short*)wt;
    int rowbase = blockIdx.x * 64, colbase = blockIdx.y * 128;
    f32x16 acc0, acc1;
    gemm_tile2(A, W, 384, rowbase, colbase, als, wls, acc0, acc1);
    int tid = threadIdx.x, wid = tid >> 6, lane = tid & 63;
    int hi = lane >> 5, l31 = lane & 31;
    int wm = wid >> 1, wn = wid & 1;
    int c0 = colbase + wn * 64 + l31;       // 0..767
    int c1 = c0 + 32;
    float bs0 = bias[c0];
    float bs1 = bias[c1];
#pragma unroll
    for (int i = 0; i < 16; ++i) {
        int mrow = (i & 3) + 8 * (i >> 2) + 4 * hi;
        int row = rowbase + wm * 32 + mrow;
        float v0 = acc0[i] + bs0;
        float v1 = acc1[i] + bs1;
        float g0 = 0.5f * v0 * (1.f + erff(v0 * 0.70710678118f));
        float g1 = 0.5f * v1 * (1.f + erff(v1 * 0.70710678118f));
        h[(size_t)row * 768 + c0] = f2b(g0);
        h[(size_t)row * 768 + c1] = f2b(g1);
    }
}

// ================= K7: FC2 GEMM (MFMA) + bias + residual -> split fp32 outputs =================
__global__ __launch_bounds__(256) void k_fc2_m(const bf16* __restrict__ h, const bf16* __restrict__ wt,
                                               const float* __restrict__ bias, const float* __restrict__ xc,
                                               float* __restrict__ outp) {
    __shared__ short als[64 * 64];
    __shared__ short wls[64 * 64];
    const short* A = (const short*)h;
    const short* W = (const short*)wt;
    int rowbase = blockIdx.x * 64, colbase = blockIdx.y * 64;
    f32x16 acc = gemm_tile(A, W, 768, rowbase, colbase, als, wls);
    int tid = threadIdx.x, wid = tid >> 6, lane = tid & 63;
    int hi = lane >> 5, l31 = lane & 31;
    int wm = wid >> 1, wn = wid & 1;
    int c = colbase + wn * 32 + l31;        // 0..383
    float bs = bias[c];
    int which = c >> 7, cc = c & 127;
#pragma unroll
    for (int i = 0; i < 16; ++i) {
        int mrow = (i & 3) + 8 * (i >> 2) + 4 * hi;
        int row = rowbase + wm * 32 + mrow;
        outp[(size_t)which * 524288 + (size_t)row * 128 + cc] = acc[i] + bs + xc[(size_t)row * 384 + c];
    }
}

// ================= launch =================
extern "C" void kernel_launch(void* const* d_in, const int* in_sizes, int n_in,
                              void* d_out, int out_size, void* d_ws, size_t ws_size,
                              hipStream_t stream) {
    const float* x1     = (const float*)d_in[0];
    const float* x2     = (const float*)d_in[1];
    const float* x3     = (const float*)d_in[2];
    const float* ln1_g  = (const float*)d_in[3];
    const float* ln1_b  = (const float*)d_in[4];
    const float* qkv_w  = (const float*)d_in[5];
    const float* proj_w = (const float*)d_in[6];
    const float* proj_b = (const float*)d_in[7];
    const float* ln2_g  = (const float*)d_in[8];
    const float* ln2_b  = (const float*)d_in[9];
    const float* fc1_w  = (const float*)d_in[10];
    const float* fc1_b  = (const float*)d_in[11];
    const float* fc2_w  = (const float*)d_in[12];
    const float* fc2_b  = (const float*)d_in[13];

    char* ws = (char*)d_ws;
    const size_t SB = 3145728;  // bf16 buffer of 1.5M elems
    bf16* xn  = (bf16*)(ws + 0 * SB);
    bf16* qb  = (bf16*)(ws + 1 * SB);
    bf16* kb  = (bf16*)(ws + 2 * SB);
    bf16* vb  = (bf16*)(ws + 3 * SB);   // tiled V^T
    float* xc = (float*)(ws + 5 * SB);            // 4096*384*4 = 6291456 B
    bf16* xcn = (bf16*)(ws + 5 * SB + 6291456);   // 3145728 B
    bf16* hb  = (bf16*)(ws + 6 * SB + 6291456);   // 4096*768*2 = 6291456 B
    char* wbase = ws + 31457280;
    bf16* wtq = (bf16*)(wbase);                   // 3*384*128*2 = 294912
    bf16* wtp = (bf16*)(wbase + 294912);          // 3*128*128*2 = 98304
    bf16* wt1 = (bf16*)(wbase + 393216);          // 768*384*2   = 589824
    bf16* wt2 = (bf16*)(wbase + 983040);          // 384*768*2   = 589824
    // total = 33030144 B (~31.5 MB)
    // Split-K attention partials OVERLAY xcn+hb (both written only after proj reads them):
    bf16*  pacc = (bf16*)(ws + 22020096);         // 2*48*2048*16*2 = 6291456 B
    float2* psm = (float2*)(ws + 28311552);       // 2*48*2048*8    = 1572864 B

    k_pre<<<6144, 256, 0, stream>>>(x1, x2, x3, ln1_g, ln1_b, xn,
                                    qkv_w, proj_w, fc1_w, fc2_w, wtq, wtp, wt1, wt2);
    k_qkv_m<<<dim3(64, 3, 3), 256, 0, stream>>>(xn, wtq, qb, kb, vb);
    k_attn<<<dim3(48, 16, 2), 128, 0, stream>>>(qb, kb, vb, pacc, psm);
    k_proj_m<<<dim3(64, 2, 3), 256, 0, stream>>>(pacc, psm, wtp, proj_b, x1, x2, x3, xc);
    k_ln2<<<1024, 256, 0, stream>>>(xc, ln2_g, ln2_b, xcn);
    k_fc1_m<<<dim3(64, 6, 1), 256, 0, stream>>>(xcn, wt1, fc1_b, hb);
    k_fc2_m<<<dim3(64, 6, 1), 256, 0, stream>>>(hb, wt2, fc2_b, xc, (float*)d_out);
}